// Round 5
// baseline (489.290 us; speedup 1.0000x reference)
//
#include <hip/hip_runtime.h>
#include <hip/hip_bf16.h>

// EarthAttention3D (Pangu): B_=30, nW=32, N=144, C=192, H=6, hd=32
#define DIM    192
#define HEADS  6
#define HD     32
#define NTOK   144                  // tokens per window
#define NWIN   960                  // 30 lon * 32 window-types
#define NBWH   (NWIN * HEADS)       // 5760
#define TOKENS (NWIN * NTOK)        // 138240
#define PPITCH 168                  // attn LDS row pitch (halves)
#define XPITCH 200                  // gemm LDS x-tile pitch (halves): 100 dwords %32=4 -> 2-way max (free)
#define NTILE  (TOKENS / 32)        // 4320 token tiles
#define QKV_GRID  512
#define PROJ_GRID 1024
#define LOG2E  1.4426950408889634f  // softmax done in exp2 domain (v_exp_f32 is 2^x)

typedef __attribute__((ext_vector_type(8))) short bf16x8;   // MFMA A/B frag (4 VGPRs)
typedef __attribute__((ext_vector_type(4))) float f32x4;    // MFMA C/D frag
typedef __attribute__((ext_vector_type(4))) short short4v;  // 8 B vector store

static __device__ __forceinline__ short f2bf(float f) {
  __hip_bfloat16 h = __float2bfloat16(f);      // RTN
  return __builtin_bit_cast(short, h);
}
static __device__ __forceinline__ float bf2f(short s) {
  unsigned u = ((unsigned)(unsigned short)s) << 16;
  return __builtin_bit_cast(float, u);
}

// ---------------------------------------------------------------------------
// prep: bf16 weight casts + TRANSPOSED bias/mask expansion.
// biasT[w][h][key][query], maskT[bw][key][query]  (bf16) — so attn can load
// 4 consecutive query rows per lane as one short4. bias/mask are pre-scaled
// by LOG2E so attn's softmax can use raw v_exp_f32 (2^x) with no per-element
// multiply.
// ---------------------------------------------------------------------------
#define NBIAS (32 * HEADS * NTOK * NTOK)   // 3,981,312
#define NMASK (NWIN * NTOK * NTOK)         // 19,906,560
#define NWQ   (3 * DIM * DIM)              // 110,592
#define NWP   (DIM * DIM)                  // 36,864
#define NB8   (NBIAS / 8)
#define NM8   (NMASK / 8)
#define NWQ8  (NWQ / 8)
#define NWP8  (NWP / 8)

__global__ __launch_bounds__(256) void prep_kernel(
    const float* __restrict__ qkv_w, const float* __restrict__ proj_w,
    const float* __restrict__ bias_table, const int* __restrict__ pos_index,
    const float* __restrict__ mask,
    short* __restrict__ wq_b, short* __restrict__ wp_b,
    short* __restrict__ biasT, short* __restrict__ maskT)
{
  int i = blockIdx.x * 256 + threadIdx.x;
  if (i < NB8) {
    // one thread: 8 consecutive queries at fixed (w,h,key)
    int flat = i * 8;
    int q0 = flat % NTOK;
    int t  = flat / NTOK;
    int kk = t % NTOK;
    int t2 = t / NTOK;
    int h  = t2 % HEADS;
    int w  = t2 / HEADS;
    bf16x8 o;
#pragma unroll
    for (int jj = 0; jj < 8; ++jj) {
      int pos = pos_index[(q0 + jj) * NTOK + kk];
      o[jj] = f2bf(bias_table[(size_t)pos * (32 * HEADS) + w * HEADS + h] * LOG2E);
    }
    *(bf16x8*)(biasT + (size_t)((w * HEADS + h) * NTOK + kk) * NTOK + q0) = o;
  } else if (i < NB8 + NM8) {
    int flat = (i - NB8) * 8;
    int q0 = flat % NTOK;
    int t  = flat / NTOK;
    int kk = t % NTOK;
    int bw = t / NTOK;
    bf16x8 o;
#pragma unroll
    for (int jj = 0; jj < 8; ++jj)
      o[jj] = f2bf(mask[((size_t)bw * NTOK + q0 + jj) * NTOK + kk] * LOG2E);
    *(bf16x8*)(maskT + ((size_t)bw * NTOK + kk) * NTOK + q0) = o;
  } else if (i < NB8 + NM8 + NWQ8) {
    int flat = (i - NB8 - NM8) * 8;
    float4 f0 = *(const float4*)(qkv_w + flat);
    float4 f1 = *(const float4*)(qkv_w + flat + 4);
    bf16x8 o;
    o[0]=f2bf(f0.x); o[1]=f2bf(f0.y); o[2]=f2bf(f0.z); o[3]=f2bf(f0.w);
    o[4]=f2bf(f1.x); o[5]=f2bf(f1.y); o[6]=f2bf(f1.z); o[7]=f2bf(f1.w);
    *(bf16x8*)(wq_b + flat) = o;
  } else if (i < NB8 + NM8 + NWQ8 + NWP8) {
    int flat = (i - NB8 - NM8 - NWQ8) * 8;
    float4 f0 = *(const float4*)(proj_w + flat);
    float4 f1 = *(const float4*)(proj_w + flat + 4);
    bf16x8 o;
    o[0]=f2bf(f0.x); o[1]=f2bf(f0.y); o[2]=f2bf(f0.z); o[3]=f2bf(f0.w);
    o[4]=f2bf(f1.x); o[5]=f2bf(f1.y); o[6]=f2bf(f1.z); o[7]=f2bf(f1.w);
    *(bf16x8*)(wp_b + flat) = o;
  }
}

// ---------------------------------------------------------------------------
// QKV GEMM (R3): weights RESIDENT IN REGISTERS.
// Block = 768 thr (12 waves); wave owns 48 out-channels -> its full 48x192
// weight slice = 18 bf16x8 frags (72 VGPR), loaded ONCE. Grid-stride over
// 32-token tiles with double-buffered LDS x staging (load-early/write-late).
// dst (q/k/v) is wave-uniform: waves 0-3 -> q, 4-7 -> k, 8-11 -> v.
// q additionally folds scale = 32^-0.5 * LOG2E (exp2-domain softmax).
// ---------------------------------------------------------------------------
__global__ __launch_bounds__(768, 3) void qkv_gemm(
    const float* __restrict__ x, const short* __restrict__ wq,
    const float* __restrict__ qbias,
    short* __restrict__ q, short* __restrict__ k, short* __restrict__ v)
{
  __shared__ __align__(16) short xs[2][32 * XPITCH];

  const int wave = threadIdx.x >> 6, lane = threadIdx.x & 63;
  const int m = lane & 15, g = lane >> 4;
  const int c0w = wave * 48;

  // persistent weight fragments: 48 ch x 192 k per wave
  bf16x8 wfrag[3][6];
#pragma unroll
  for (int ct = 0; ct < 3; ++ct)
#pragma unroll
    for (int ks = 0; ks < 6; ++ks)
      wfrag[ct][ks] = *(const bf16x8*)(wq + (size_t)(c0w + ct * 16 + m) * DIM + ks * 32 + g * 8);

  const int which = wave >> 2;                  // 0=q 1=k 2=v (wave-uniform)
  short* dst = which == 0 ? q : (which == 1 ? k : v);
  const float sc = which == 0 ? (0.17677669529663689f * LOG2E) : 1.0f;

  float4 b4[3];
  int hh[3], d0[3];
#pragma unroll
  for (int ct = 0; ct < 3; ++ct) {
    int co0 = c0w + ct * 16 + g * 4;
    b4[ct] = *(const float4*)(qbias + co0);
    int rem = co0 - which * DIM;
    hh[ct] = rem >> 5; d0[ct] = rem & 31;
  }

  // staging coords: 768 thr = 32 rows x 24 col-groups of 8 floats
  const int srow = threadIdx.x / 24;
  const int scg  = threadIdx.x % 24;

  { // prologue: stage first tile into buf 0
    const float* xp = x + ((size_t)(blockIdx.x * 32 + srow)) * DIM + scg * 8;
    float4 f0 = ((const float4*)xp)[0];
    float4 f1 = ((const float4*)xp)[1];
    bf16x8 o;
    o[0]=f2bf(f0.x); o[1]=f2bf(f0.y); o[2]=f2bf(f0.z); o[3]=f2bf(f0.w);
    o[4]=f2bf(f1.x); o[5]=f2bf(f1.y); o[6]=f2bf(f1.z); o[7]=f2bf(f1.w);
    *(bf16x8*)(&xs[0][srow * XPITCH + scg * 8]) = o;
  }
  __syncthreads();

  int cur = 0;
  for (int t = blockIdx.x; t < NTILE; t += QKV_GRID) {
    const int tn = t + QKV_GRID;
    const bool have = tn < NTILE;
    float4 f0, f1;
    if (have) {       // issue next-tile loads EARLY (overlap with MFMA below)
      const float* xp = x + ((size_t)(tn * 32 + srow)) * DIM + scg * 8;
      f0 = ((const float4*)xp)[0];
      f1 = ((const float4*)xp)[1];
    }

    f32x4 acc[3][2];
#pragma unroll
    for (int ct = 0; ct < 3; ++ct)
#pragma unroll
      for (int rt = 0; rt < 2; ++rt) acc[ct][rt] = (f32x4){0.f, 0.f, 0.f, 0.f};

#pragma unroll
    for (int ks = 0; ks < 6; ++ks) {
      const short* bp_ = &xs[cur][m * XPITCH + ks * 32 + g * 8];
      bf16x8 b0 = *(const bf16x8*)bp_;
      bf16x8 b1 = *(const bf16x8*)(bp_ + 16 * XPITCH);
#pragma unroll
      for (int ct = 0; ct < 3; ++ct) {
        acc[ct][0] = __builtin_amdgcn_mfma_f32_16x16x32_bf16(wfrag[ct][ks], b0, acc[ct][0], 0, 0, 0);
        acc[ct][1] = __builtin_amdgcn_mfma_f32_16x16x32_bf16(wfrag[ct][ks], b1, acc[ct][1], 0, 0, 0);
      }
    }

#pragma unroll
    for (int ct = 0; ct < 3; ++ct) {
#pragma unroll
      for (int rt = 0; rt < 2; ++rt) {
        int tok = t * 32 + rt * 16 + m;
        int bw = tok / NTOK, n = tok - bw * NTOK;
        short4v s;
        s[0] = f2bf((acc[ct][rt][0] + b4[ct].x) * sc);
        s[1] = f2bf((acc[ct][rt][1] + b4[ct].y) * sc);
        s[2] = f2bf((acc[ct][rt][2] + b4[ct].z) * sc);
        s[3] = f2bf((acc[ct][rt][3] + b4[ct].w) * sc);
        *(short4v*)(dst + ((size_t)(bw * HEADS + hh[ct]) * NTOK + n) * HD + d0[ct]) = s;
      }
    }

    if (have) {       // write-late: cvt + ds_write into the other buffer
      bf16x8 o;
      o[0]=f2bf(f0.x); o[1]=f2bf(f0.y); o[2]=f2bf(f0.z); o[3]=f2bf(f0.w);
      o[4]=f2bf(f1.x); o[5]=f2bf(f1.y); o[6]=f2bf(f1.z); o[7]=f2bf(f1.w);
      *(bf16x8*)(&xs[cur ^ 1][srow * XPITCH + scg * 8]) = o;
    }
    __syncthreads();
    cur ^= 1;
  }
}

// ---------------------------------------------------------------------------
// Attention: block = one (bw, h); 192 thr = 3 waves x 3 row-tiles of 16 rows.
// R4: XCD-grouping swizzle — blockIdx%8 selects the XCD (HW round-robin), so
// map b -> (bw,h) with all 6 heads of one bw at the same b%8 residue. The
// 41.4 KB maskT slice is then fetched from HBM once per group instead of 6x
// (R3 counters: FETCH 425 MB vs 207 MB unique = mask re-fetched per XCD).
// 5760 = 8 xcd * 120 groups * 6 heads, exact and bijective.
// Softmax in exp2 domain (scales pre-folded by prep/qkv).
// ---------------------------------------------------------------------------
__global__ __launch_bounds__(192, 3) void attn_kernel(
    const short* __restrict__ q, const short* __restrict__ k,
    const short* __restrict__ v, const short* __restrict__ biasT,
    const short* __restrict__ maskT, short* __restrict__ aout)
{
  const int b    = blockIdx.x;
  const int xcd  = b & 7;
  const int slot = b >> 3;                   // 0..719
  const int bw   = xcd * 120 + slot / 6;     // 6 heads of one bw share an XCD
  const int h    = slot % 6;
  const int bwh  = bw * HEADS + h;
  const int w    = bw & 31;                  // window-type; lon = bw>>5

  __shared__ __align__(16) short vt[HD * PPITCH];       // v transposed [d][n]
  __shared__ __align__(16) short pl[3 * 16 * PPITCH];   // per-wave P tile

  const size_t base = (size_t)bwh * (NTOK * HD);
  const short* qb = q + base;
  const short* kb = k + base;
  const short* vb = v + base;

  // stage v -> vt[d][n]
  for (int i = threadIdx.x; i < (NTOK * HD) / 8; i += 192) {
    int n = i >> 2, dg = (i & 3) * 8;
    bf16x8 vv = *(const bf16x8*)(vb + n * HD + dg);
#pragma unroll
    for (int j = 0; j < 8; ++j) vt[(dg + j) * PPITCH + n] = vv[j];
  }
  // zero K-pad cols 144..160 of vt
  for (int i = threadIdx.x; i < 128; i += 192) {
    int d = i >> 2, c = 144 + (i & 3) * 4;
    *(short4v*)&vt[d * PPITCH + c] = (short4v){0, 0, 0, 0};
  }
  __syncthreads();

  const int wv = threadIdx.x >> 6;
  const int lane = threadIdx.x & 63;
  const int m = lane & 15, g = lane >> 4;
  short* myp = pl + wv * 16 * PPITCH;
  { // zero K-pad of own wave's P rows
    int r = lane >> 2, c = 144 + (lane & 3) * 4;
    *(short4v*)&myp[r * PPITCH + c] = (short4v){0, 0, 0, 0};
  }

  const short* bp = biasT + (size_t)(w * HEADS + h) * (NTOK * NTOK);  // [key][query]
  const short* mp = maskT + (size_t)bw * (NTOK * NTOK);               // [key][query]

  for (int rt = wv * 3; rt < wv * 3 + 3; ++rt) {
    const int i0 = rt * 16;
    bf16x8 aq = *(const bf16x8*)(qb + (size_t)(i0 + m) * HD + g * 8);
    f32x4 s[9];
#pragma unroll
    for (int jt = 0; jt < 9; ++jt) {
      bf16x8 bk = *(const bf16x8*)(kb + (size_t)(jt * 16 + m) * HD + g * 8);
      s[jt] = __builtin_amdgcn_mfma_f32_16x16x32_bf16(aq, bk, (f32x4){0.f, 0.f, 0.f, 0.f}, 0, 0, 0);
    }
    // bias + mask (short4: 4 consecutive query rows at fixed key) + row max
    float mx[4] = {-3e38f, -3e38f, -3e38f, -3e38f};
#pragma unroll
    for (int jt = 0; jt < 9; ++jt) {
      int key = jt * 16 + m;
      short4v bb = *(const short4v*)(bp + key * NTOK + i0 + g * 4);
      short4v mm = *(const short4v*)(mp + key * NTOK + i0 + g * 4);
#pragma unroll
      for (int r = 0; r < 4; ++r) {
        float val = s[jt][r] + bf2f(bb[r]) + bf2f(mm[r]);
        s[jt][r] = val;
        mx[r] = fmaxf(mx[r], val);
      }
    }
#pragma unroll
    for (int r = 0; r < 4; ++r) {
      mx[r] = fmaxf(mx[r], __shfl_xor(mx[r], 1, 64));
      mx[r] = fmaxf(mx[r], __shfl_xor(mx[r], 2, 64));
      mx[r] = fmaxf(mx[r], __shfl_xor(mx[r], 4, 64));
      mx[r] = fmaxf(mx[r], __shfl_xor(mx[r], 8, 64));
    }
    float sum[4] = {0.f, 0.f, 0.f, 0.f};
#pragma unroll
    for (int jt = 0; jt < 9; ++jt) {
#pragma unroll
      for (int r = 0; r < 4; ++r) {
        float e = __builtin_amdgcn_exp2f(s[jt][r] - mx[r]);   // v_exp_f32: 2^x == e^orig (scales pre-folded)
        s[jt][r] = e;
        sum[r] += e;
      }
    }
#pragma unroll
    for (int r = 0; r < 4; ++r) {
      sum[r] += __shfl_xor(sum[r], 1, 64);
      sum[r] += __shfl_xor(sum[r], 2, 64);
      sum[r] += __shfl_xor(sum[r], 4, 64);
      sum[r] += __shfl_xor(sum[r], 8, 64);
    }
    float rs[4];
#pragma unroll
    for (int r = 0; r < 4; ++r) rs[r] = 1.0f / sum[r];
    // normalized P -> LDS bf16
#pragma unroll
    for (int jt = 0; jt < 9; ++jt)
#pragma unroll
      for (int r = 0; r < 4; ++r)
        myp[(g * 4 + r) * PPITCH + jt * 16 + m] = f2bf(s[jt][r] * rs[r]);

    // O^T = V^T @ P^T (operand-swapped): D rows = d-channels, cols = queries.
    f32x4 o0 = (f32x4){0.f, 0.f, 0.f, 0.f};
    f32x4 o1 = (f32x4){0.f, 0.f, 0.f, 0.f};
#pragma unroll
    for (int kt = 0; kt < 5; ++kt) {
      bf16x8 ap = *(const bf16x8*)(myp + m * PPITCH + kt * 32 + g * 8);
      bf16x8 b0 = *(const bf16x8*)(vt + m * PPITCH + kt * 32 + g * 8);
      bf16x8 b1 = *(const bf16x8*)(vt + (16 + m) * PPITCH + kt * 32 + g * 8);
      o0 = __builtin_amdgcn_mfma_f32_16x16x32_bf16(b0, ap, o0, 0, 0, 0);
      o1 = __builtin_amdgcn_mfma_f32_16x16x32_bf16(b1, ap, o1, 0, 0, 0);
    }
    // lane: token = i0+m, d = g*4+r (o0) / 16+g*4+r (o1) -> two short4 stores
    size_t ob = ((size_t)(bw * NTOK + i0 + m)) * DIM + h * HD + g * 4;
    short4v s0, s1;
#pragma unroll
    for (int r = 0; r < 4; ++r) { s0[r] = f2bf(o0[r]); s1[r] = f2bf(o1[r]); }
    *(short4v*)(aout + ob) = s0;
    *(short4v*)(aout + ob + 16) = s1;
  }
}

// ---------------------------------------------------------------------------
// Proj GEMM (R3): same template as qkv_gemm. Block = 256 thr
// (4 waves x 48 ch = 192 out-ch); wave's 48x192 weight slice resident in
// registers (18 frags); grid-stride over 32-token tiles, double-buffered LDS
// ain staging with load-early/write-late. Lane stores float4 (16 B).
// ---------------------------------------------------------------------------
__global__ __launch_bounds__(256, 3) void proj_gemm(
    const short* __restrict__ ain, const short* __restrict__ pw,
    const float* __restrict__ pb, float* __restrict__ out)
{
  __shared__ __align__(16) short as_[2][32 * XPITCH];

  const int wave = threadIdx.x >> 6, lane = threadIdx.x & 63;
  const int m = lane & 15, g = lane >> 4;
  const int c0w = wave * 48;

  bf16x8 wfrag[3][6];
#pragma unroll
  for (int ct = 0; ct < 3; ++ct)
#pragma unroll
    for (int ks = 0; ks < 6; ++ks)
      wfrag[ct][ks] = *(const bf16x8*)(pw + (size_t)(c0w + ct * 16 + m) * DIM + ks * 32 + g * 8);

  float4 b4[3];
#pragma unroll
  for (int ct = 0; ct < 3; ++ct)
    b4[ct] = *(const float4*)(pb + c0w + ct * 16 + g * 4);

  // staging coords: 256 thr = 32 rows x 8 groups of 24 shorts (bf16 copy)
  const int srow = threadIdx.x >> 3;
  const int scg  = threadIdx.x & 7;

  { // prologue: stage first tile into buf 0
    const short* sp = ain + ((size_t)(blockIdx.x * 32 + srow)) * DIM + scg * 24;
    short* dp = &as_[0][srow * XPITCH + scg * 24];
#pragma unroll
    for (int i = 0; i < 3; ++i)
      *(bf16x8*)(dp + i * 8) = *(const bf16x8*)(sp + i * 8);
  }
  __syncthreads();

  int cur = 0;
  for (int t = blockIdx.x; t < NTILE; t += PROJ_GRID) {
    const int tn = t + PROJ_GRID;
    const bool have = tn < NTILE;
    bf16x8 r0, r1, r2;
    if (have) {       // issue next-tile loads early
      const short* sp = ain + ((size_t)(tn * 32 + srow)) * DIM + scg * 24;
      r0 = *(const bf16x8*)(sp);
      r1 = *(const bf16x8*)(sp + 8);
      r2 = *(const bf16x8*)(sp + 16);
    }

    f32x4 acc[3][2];
#pragma unroll
    for (int ct = 0; ct < 3; ++ct)
#pragma unroll
      for (int rt = 0; rt < 2; ++rt) acc[ct][rt] = (f32x4){0.f, 0.f, 0.f, 0.f};

#pragma unroll
    for (int ks = 0; ks < 6; ++ks) {
      const short* bp_ = &as_[cur][m * XPITCH + ks * 32 + g * 8];
      bf16x8 b0 = *(const bf16x8*)bp_;
      bf16x8 b1 = *(const bf16x8*)(bp_ + 16 * XPITCH);
#pragma unroll
      for (int ct = 0; ct < 3; ++ct) {
        acc[ct][0] = __builtin_amdgcn_mfma_f32_16x16x32_bf16(wfrag[ct][ks], b0, acc[ct][0], 0, 0, 0);
        acc[ct][1] = __builtin_amdgcn_mfma_f32_16x16x32_bf16(wfrag[ct][ks], b1, acc[ct][1], 0, 0, 0);
      }
    }

#pragma unroll
    for (int ct = 0; ct < 3; ++ct) {
      int co0 = c0w + ct * 16 + g * 4;
#pragma unroll
      for (int rt = 0; rt < 2; ++rt) {
        int tok = t * 32 + rt * 16 + m;
        float4 o;
        o.x = acc[ct][rt][0] + b4[ct].x;
        o.y = acc[ct][rt][1] + b4[ct].y;
        o.z = acc[ct][rt][2] + b4[ct].z;
        o.w = acc[ct][rt][3] + b4[ct].w;
        *(float4*)(out + (size_t)tok * DIM + co0) = o;
      }
    }

    if (have) {       // write-late into other buffer
      short* dp = &as_[cur ^ 1][srow * XPITCH + scg * 24];
      *(bf16x8*)(dp)      = r0;
      *(bf16x8*)(dp + 8)  = r1;
      *(bf16x8*)(dp + 16) = r2;
    }
    __syncthreads();
    cur ^= 1;
  }
}

// ---------------------------------------------------------------------------
extern "C" void kernel_launch(void* const* d_in, const int* in_sizes, int n_in,
                              void* d_out, int out_size, void* d_ws, size_t ws_size,
                              hipStream_t stream) {
  const float* x          = (const float*)d_in[0];
  const float* mask       = (const float*)d_in[1];
  const float* qkv_w      = (const float*)d_in[2];
  const float* qkv_b      = (const float*)d_in[3];
  const float* proj_w     = (const float*)d_in[4];
  const float* proj_b     = (const float*)d_in[5];
  const float* bias_table = (const float*)d_in[6];
  const int*   pos_index  = (const int*)d_in[7];
  float* out = (float*)d_out;

  // workspace carve (16B-aligned)
  const size_t NELEM = (size_t)TOKENS * DIM;   // 26,542,080
  short* qv    = (short*)d_ws;
  short* kv    = qv + NELEM;
  short* vv    = kv + NELEM;
  short* aout  = vv + NELEM;
  short* wqb   = aout + NELEM;
  short* wpb   = wqb + NWQ;
  short* biasT = wpb + NWP;
  short* maskT = biasT + NBIAS;
  // total = 4*NELEM + NWQ + NWP + NBIAS + NMASK shorts ≈ 260.4 MB

  prep_kernel<<<(NB8 + NM8 + NWQ8 + NWP8 + 255) / 256, 256, 0, stream>>>(
      qkv_w, proj_w, bias_table, pos_index, mask, wqb, wpb, biasT, maskT);
  qkv_gemm<<<QKV_GRID, 768, 0, stream>>>(x, wqb, qkv_b, qv, kv, vv);
  attn_kernel<<<NBWH, 192, 0, stream>>>(qv, kv, vv, biasT, maskT, aout);
  proj_gemm<<<PROJ_GRID, 256, 0, stream>>>(aout, wpb, proj_b, out);
}

// Round 6
// 444.834 us; speedup vs baseline: 1.0999x; 1.0999x over previous
//
#include <hip/hip_runtime.h>
#include <hip/hip_bf16.h>

// EarthAttention3D (Pangu): B_=30, nW=32, N=144, C=192, H=6, hd=32
#define DIM    192
#define HEADS  6
#define HD     32
#define NTOK   144                  // tokens per window
#define NWIN   960                  // 30 lon * 32 window-types
#define NBWH   (NWIN * HEADS)       // 5760
#define TOKENS (NWIN * NTOK)        // 138240
#define PPITCH 168                  // attn LDS row pitch (halves)
#define XPITCH 200                  // gemm LDS x-tile pitch (halves): 100 dwords %32=4 -> 2-way max (free)
#define NTILE  (TOKENS / 32)        // 4320 token tiles
#define QKV_GRID  512
#define PROJ_GRID 1024
#define LOG2E  1.4426950408889634f  // softmax done in exp2 domain (v_exp_f32 is 2^x)

typedef __attribute__((ext_vector_type(8))) short bf16x8;   // MFMA A/B frag (4 VGPRs)
typedef __attribute__((ext_vector_type(4))) float f32x4;    // MFMA C/D frag
typedef __attribute__((ext_vector_type(4))) short short4v;  // 8 B vector store

static __device__ __forceinline__ short f2bf(float f) {
  __hip_bfloat16 h = __float2bfloat16(f);      // RTN
  return __builtin_bit_cast(short, h);
}
static __device__ __forceinline__ float bf2f(short s) {
  unsigned u = ((unsigned)(unsigned short)s) << 16;
  return __builtin_bit_cast(float, u);
}

// ---------------------------------------------------------------------------
// prep: bf16 weight casts + TILE-BLOCKED bias/mask expansion.
// R6: biasT[wh][qtile][key][q16], maskT[bw][qtile][key][q16] (q16 = query
// within the 16-query rt tile). Per (block, rt, jt) the attn wave now reads
// 512 CONTIGUOUS bytes (16 keys x 32 B) with every fetched byte used once.
// The R3-R5 [key][query] layout used only 32 B of each 288 B row per visit;
// L2 thrash between visits re-fetched each 128 B line up to 4x (FETCH 413 MB
// vs 207 MB unique, unchanged by XCD swizzle -> line-waste, not duplication).
// bias/mask pre-scaled by LOG2E for exp2-domain softmax.
// ---------------------------------------------------------------------------
#define NBIAS (32 * HEADS * NTOK * NTOK)   // 3,981,312
#define NMASK (NWIN * NTOK * NTOK)         // 19,906,560
#define NWQ   (3 * DIM * DIM)              // 110,592
#define NWP   (DIM * DIM)                  // 36,864
#define NB8   (NBIAS / 8)
#define NM8   (NMASK / 8)
#define NWQ8  (NWQ / 8)
#define NWP8  (NWP / 8)

__global__ __launch_bounds__(256) void prep_kernel(
    const float* __restrict__ qkv_w, const float* __restrict__ proj_w,
    const float* __restrict__ bias_table, const int* __restrict__ pos_index,
    const float* __restrict__ mask,
    short* __restrict__ wq_b, short* __restrict__ wp_b,
    short* __restrict__ biasT, short* __restrict__ maskT)
{
  int i = blockIdx.x * 256 + threadIdx.x;
  if (i < NB8) {
    // one thread: 8 consecutive queries at fixed (w,h,key); q0 % 8 == 0 so
    // the 8 queries stay inside one 16-query tile half (q0%16 in {0,8}).
    int flat = i * 8;
    int q0 = flat % NTOK;
    int t  = flat / NTOK;
    int kk = t % NTOK;
    int t2 = t / NTOK;
    int h  = t2 % HEADS;
    int w  = t2 / HEADS;
    bf16x8 o;
#pragma unroll
    for (int jj = 0; jj < 8; ++jj) {
      int pos = pos_index[(q0 + jj) * NTOK + kk];
      o[jj] = f2bf(bias_table[(size_t)pos * (32 * HEADS) + w * HEADS + h] * LOG2E);
    }
    // [wh][q0/16][kk][q0%16]
    *(bf16x8*)(biasT + ((size_t)((w * HEADS + h) * 9 + (q0 >> 4)) * NTOK + kk) * 16 + (q0 & 15)) = o;
  } else if (i < NB8 + NM8) {
    int flat = (i - NB8) * 8;
    int q0 = flat % NTOK;
    int t  = flat / NTOK;
    int kk = t % NTOK;
    int bw = t / NTOK;
    bf16x8 o;
#pragma unroll
    for (int jj = 0; jj < 8; ++jj)
      o[jj] = f2bf(mask[((size_t)bw * NTOK + q0 + jj) * NTOK + kk] * LOG2E);
    // [bw][q0/16][kk][q0%16]
    *(bf16x8*)(maskT + ((size_t)(bw * 9 + (q0 >> 4)) * NTOK + kk) * 16 + (q0 & 15)) = o;
  } else if (i < NB8 + NM8 + NWQ8) {
    int flat = (i - NB8 - NM8) * 8;
    float4 f0 = *(const float4*)(qkv_w + flat);
    float4 f1 = *(const float4*)(qkv_w + flat + 4);
    bf16x8 o;
    o[0]=f2bf(f0.x); o[1]=f2bf(f0.y); o[2]=f2bf(f0.z); o[3]=f2bf(f0.w);
    o[4]=f2bf(f1.x); o[5]=f2bf(f1.y); o[6]=f2bf(f1.z); o[7]=f2bf(f1.w);
    *(bf16x8*)(wq_b + flat) = o;
  } else if (i < NB8 + NM8 + NWQ8 + NWP8) {
    int flat = (i - NB8 - NM8 - NWQ8) * 8;
    float4 f0 = *(const float4*)(proj_w + flat);
    float4 f1 = *(const float4*)(proj_w + flat + 4);
    bf16x8 o;
    o[0]=f2bf(f0.x); o[1]=f2bf(f0.y); o[2]=f2bf(f0.z); o[3]=f2bf(f0.w);
    o[4]=f2bf(f1.x); o[5]=f2bf(f1.y); o[6]=f2bf(f1.z); o[7]=f2bf(f1.w);
    *(bf16x8*)(wp_b + flat) = o;
  }
}

// ---------------------------------------------------------------------------
// QKV GEMM (R3): weights RESIDENT IN REGISTERS.
// Block = 768 thr (12 waves); wave owns 48 out-channels -> its full 48x192
// weight slice = 18 bf16x8 frags (72 VGPR), loaded ONCE. Grid-stride over
// 32-token tiles with double-buffered LDS x staging (load-early/write-late).
// dst (q/k/v) is wave-uniform: waves 0-3 -> q, 4-7 -> k, 8-11 -> v.
// q additionally folds scale = 32^-0.5 * LOG2E (exp2-domain softmax).
// ---------------------------------------------------------------------------
__global__ __launch_bounds__(768, 3) void qkv_gemm(
    const float* __restrict__ x, const short* __restrict__ wq,
    const float* __restrict__ qbias,
    short* __restrict__ q, short* __restrict__ k, short* __restrict__ v)
{
  __shared__ __align__(16) short xs[2][32 * XPITCH];

  const int wave = threadIdx.x >> 6, lane = threadIdx.x & 63;
  const int m = lane & 15, g = lane >> 4;
  const int c0w = wave * 48;

  // persistent weight fragments: 48 ch x 192 k per wave
  bf16x8 wfrag[3][6];
#pragma unroll
  for (int ct = 0; ct < 3; ++ct)
#pragma unroll
    for (int ks = 0; ks < 6; ++ks)
      wfrag[ct][ks] = *(const bf16x8*)(wq + (size_t)(c0w + ct * 16 + m) * DIM + ks * 32 + g * 8);

  const int which = wave >> 2;                  // 0=q 1=k 2=v (wave-uniform)
  short* dst = which == 0 ? q : (which == 1 ? k : v);
  const float sc = which == 0 ? (0.17677669529663689f * LOG2E) : 1.0f;

  float4 b4[3];
  int hh[3], d0[3];
#pragma unroll
  for (int ct = 0; ct < 3; ++ct) {
    int co0 = c0w + ct * 16 + g * 4;
    b4[ct] = *(const float4*)(qbias + co0);
    int rem = co0 - which * DIM;
    hh[ct] = rem >> 5; d0[ct] = rem & 31;
  }

  // staging coords: 768 thr = 32 rows x 24 col-groups of 8 floats
  const int srow = threadIdx.x / 24;
  const int scg  = threadIdx.x % 24;

  { // prologue: stage first tile into buf 0
    const float* xp = x + ((size_t)(blockIdx.x * 32 + srow)) * DIM + scg * 8;
    float4 f0 = ((const float4*)xp)[0];
    float4 f1 = ((const float4*)xp)[1];
    bf16x8 o;
    o[0]=f2bf(f0.x); o[1]=f2bf(f0.y); o[2]=f2bf(f0.z); o[3]=f2bf(f0.w);
    o[4]=f2bf(f1.x); o[5]=f2bf(f1.y); o[6]=f2bf(f1.z); o[7]=f2bf(f1.w);
    *(bf16x8*)(&xs[0][srow * XPITCH + scg * 8]) = o;
  }
  __syncthreads();

  int cur = 0;
  for (int t = blockIdx.x; t < NTILE; t += QKV_GRID) {
    const int tn = t + QKV_GRID;
    const bool have = tn < NTILE;
    float4 f0, f1;
    if (have) {       // issue next-tile loads EARLY (overlap with MFMA below)
      const float* xp = x + ((size_t)(tn * 32 + srow)) * DIM + scg * 8;
      f0 = ((const float4*)xp)[0];
      f1 = ((const float4*)xp)[1];
    }

    f32x4 acc[3][2];
#pragma unroll
    for (int ct = 0; ct < 3; ++ct)
#pragma unroll
      for (int rt = 0; rt < 2; ++rt) acc[ct][rt] = (f32x4){0.f, 0.f, 0.f, 0.f};

#pragma unroll
    for (int ks = 0; ks < 6; ++ks) {
      const short* bp_ = &xs[cur][m * XPITCH + ks * 32 + g * 8];
      bf16x8 b0 = *(const bf16x8*)bp_;
      bf16x8 b1 = *(const bf16x8*)(bp_ + 16 * XPITCH);
#pragma unroll
      for (int ct = 0; ct < 3; ++ct) {
        acc[ct][0] = __builtin_amdgcn_mfma_f32_16x16x32_bf16(wfrag[ct][ks], b0, acc[ct][0], 0, 0, 0);
        acc[ct][1] = __builtin_amdgcn_mfma_f32_16x16x32_bf16(wfrag[ct][ks], b1, acc[ct][1], 0, 0, 0);
      }
    }

#pragma unroll
    for (int ct = 0; ct < 3; ++ct) {
#pragma unroll
      for (int rt = 0; rt < 2; ++rt) {
        int tok = t * 32 + rt * 16 + m;
        int bw = tok / NTOK, n = tok - bw * NTOK;
        short4v s;
        s[0] = f2bf((acc[ct][rt][0] + b4[ct].x) * sc);
        s[1] = f2bf((acc[ct][rt][1] + b4[ct].y) * sc);
        s[2] = f2bf((acc[ct][rt][2] + b4[ct].z) * sc);
        s[3] = f2bf((acc[ct][rt][3] + b4[ct].w) * sc);
        *(short4v*)(dst + ((size_t)(bw * HEADS + hh[ct]) * NTOK + n) * HD + d0[ct]) = s;
      }
    }

    if (have) {       // write-late: cvt + ds_write into the other buffer
      bf16x8 o;
      o[0]=f2bf(f0.x); o[1]=f2bf(f0.y); o[2]=f2bf(f0.z); o[3]=f2bf(f0.w);
      o[4]=f2bf(f1.x); o[5]=f2bf(f1.y); o[6]=f2bf(f1.z); o[7]=f2bf(f1.w);
      *(bf16x8*)(&xs[cur ^ 1][srow * XPITCH + scg * 8]) = o;
    }
    __syncthreads();
    cur ^= 1;
  }
}

// ---------------------------------------------------------------------------
// Attention: block = one (bw, h); 192 thr = 3 waves x 3 row-tiles of 16 rows.
// XCD-grouping swizzle (kept: same-XCD L2 sharing of the maskT slice across
// the 6 head-blocks of one bw). Bias/mask now tile-blocked: per (rt, jt) the
// wave reads 512 contiguous bytes. Softmax in exp2 domain.
// ---------------------------------------------------------------------------
__global__ __launch_bounds__(192, 3) void attn_kernel(
    const short* __restrict__ q, const short* __restrict__ k,
    const short* __restrict__ v, const short* __restrict__ biasT,
    const short* __restrict__ maskT, short* __restrict__ aout)
{
  const int b    = blockIdx.x;
  const int xcd  = b & 7;
  const int slot = b >> 3;                   // 0..719
  const int bw   = xcd * 120 + slot / 6;     // 6 heads of one bw share an XCD
  const int h    = slot % 6;
  const int bwh  = bw * HEADS + h;
  const int w    = bw & 31;                  // window-type; lon = bw>>5

  __shared__ __align__(16) short vt[HD * PPITCH];       // v transposed [d][n]
  __shared__ __align__(16) short pl[3 * 16 * PPITCH];   // per-wave P tile

  const size_t base = (size_t)bwh * (NTOK * HD);
  const short* qb = q + base;
  const short* kb = k + base;
  const short* vb = v + base;

  // stage v -> vt[d][n]
  for (int i = threadIdx.x; i < (NTOK * HD) / 8; i += 192) {
    int n = i >> 2, dg = (i & 3) * 8;
    bf16x8 vv = *(const bf16x8*)(vb + n * HD + dg);
#pragma unroll
    for (int j = 0; j < 8; ++j) vt[(dg + j) * PPITCH + n] = vv[j];
  }
  // zero K-pad cols 144..160 of vt
  for (int i = threadIdx.x; i < 128; i += 192) {
    int d = i >> 2, c = 144 + (i & 3) * 4;
    *(short4v*)&vt[d * PPITCH + c] = (short4v){0, 0, 0, 0};
  }
  __syncthreads();

  const int wv = threadIdx.x >> 6;
  const int lane = threadIdx.x & 63;
  const int m = lane & 15, g = lane >> 4;
  short* myp = pl + wv * 16 * PPITCH;
  { // zero K-pad of own wave's P rows
    int r = lane >> 2, c = 144 + (lane & 3) * 4;
    *(short4v*)&myp[r * PPITCH + c] = (short4v){0, 0, 0, 0};
  }

  // tile-blocked tables: [wh][rt][key][q16] / [bw][rt][key][q16]
  const short* bp = biasT + (size_t)(w * HEADS + h) * (9 * NTOK * 16);
  const short* mp = maskT + (size_t)bw * (9 * NTOK * 16);

  for (int rt = wv * 3; rt < wv * 3 + 3; ++rt) {
    const int i0 = rt * 16;
    const short* bpt = bp + rt * (NTOK * 16);
    const short* mpt = mp + rt * (NTOK * 16);
    bf16x8 aq = *(const bf16x8*)(qb + (size_t)(i0 + m) * HD + g * 8);
    f32x4 s[9];
#pragma unroll
    for (int jt = 0; jt < 9; ++jt) {
      bf16x8 bk = *(const bf16x8*)(kb + (size_t)(jt * 16 + m) * HD + g * 8);
      s[jt] = __builtin_amdgcn_mfma_f32_16x16x32_bf16(aq, bk, (f32x4){0.f, 0.f, 0.f, 0.f}, 0, 0, 0);
    }
    // bias + mask (short4: 4 queries at fixed key, contiguous per jt) + row max
    float mx[4] = {-3e38f, -3e38f, -3e38f, -3e38f};
#pragma unroll
    for (int jt = 0; jt < 9; ++jt) {
      int key = jt * 16 + m;
      short4v bb = *(const short4v*)(bpt + key * 16 + g * 4);
      short4v mm = *(const short4v*)(mpt + key * 16 + g * 4);
#pragma unroll
      for (int r = 0; r < 4; ++r) {
        float val = s[jt][r] + bf2f(bb[r]) + bf2f(mm[r]);
        s[jt][r] = val;
        mx[r] = fmaxf(mx[r], val);
      }
    }
#pragma unroll
    for (int r = 0; r < 4; ++r) {
      mx[r] = fmaxf(mx[r], __shfl_xor(mx[r], 1, 64));
      mx[r] = fmaxf(mx[r], __shfl_xor(mx[r], 2, 64));
      mx[r] = fmaxf(mx[r], __shfl_xor(mx[r], 4, 64));
      mx[r] = fmaxf(mx[r], __shfl_xor(mx[r], 8, 64));
    }
    float sum[4] = {0.f, 0.f, 0.f, 0.f};
#pragma unroll
    for (int jt = 0; jt < 9; ++jt) {
#pragma unroll
      for (int r = 0; r < 4; ++r) {
        float e = __builtin_amdgcn_exp2f(s[jt][r] - mx[r]);   // v_exp_f32: 2^x == e^orig (scales pre-folded)
        s[jt][r] = e;
        sum[r] += e;
      }
    }
#pragma unroll
    for (int r = 0; r < 4; ++r) {
      sum[r] += __shfl_xor(sum[r], 1, 64);
      sum[r] += __shfl_xor(sum[r], 2, 64);
      sum[r] += __shfl_xor(sum[r], 4, 64);
      sum[r] += __shfl_xor(sum[r], 8, 64);
    }
    float rs[4];
#pragma unroll
    for (int r = 0; r < 4; ++r) rs[r] = 1.0f / sum[r];
    // normalized P -> LDS bf16
#pragma unroll
    for (int jt = 0; jt < 9; ++jt)
#pragma unroll
      for (int r = 0; r < 4; ++r)
        myp[(g * 4 + r) * PPITCH + jt * 16 + m] = f2bf(s[jt][r] * rs[r]);

    // O^T = V^T @ P^T (operand-swapped): D rows = d-channels, cols = queries.
    f32x4 o0 = (f32x4){0.f, 0.f, 0.f, 0.f};
    f32x4 o1 = (f32x4){0.f, 0.f, 0.f, 0.f};
#pragma unroll
    for (int kt = 0; kt < 5; ++kt) {
      bf16x8 ap = *(const bf16x8*)(myp + m * PPITCH + kt * 32 + g * 8);
      bf16x8 b0 = *(const bf16x8*)(vt + m * PPITCH + kt * 32 + g * 8);
      bf16x8 b1 = *(const bf16x8*)(vt + (16 + m) * PPITCH + kt * 32 + g * 8);
      o0 = __builtin_amdgcn_mfma_f32_16x16x32_bf16(b0, ap, o0, 0, 0, 0);
      o1 = __builtin_amdgcn_mfma_f32_16x16x32_bf16(b1, ap, o1, 0, 0, 0);
    }
    // lane: token = i0+m, d = g*4+r (o0) / 16+g*4+r (o1) -> two short4 stores
    size_t ob = ((size_t)(bw * NTOK + i0 + m)) * DIM + h * HD + g * 4;
    short4v s0, s1;
#pragma unroll
    for (int r = 0; r < 4; ++r) { s0[r] = f2bf(o0[r]); s1[r] = f2bf(o1[r]); }
    *(short4v*)(aout + ob) = s0;
    *(short4v*)(aout + ob + 16) = s1;
  }
}

// ---------------------------------------------------------------------------
// Proj GEMM (R3): same template as qkv_gemm. Block = 256 thr
// (4 waves x 48 ch = 192 out-ch); wave's 48x192 weight slice resident in
// registers (18 frags); grid-stride over 32-token tiles, double-buffered LDS
// ain staging with load-early/write-late. Lane stores float4 (16 B).
// ---------------------------------------------------------------------------
__global__ __launch_bounds__(256, 3) void proj_gemm(
    const short* __restrict__ ain, const short* __restrict__ pw,
    const float* __restrict__ pb, float* __restrict__ out)
{
  __shared__ __align__(16) short as_[2][32 * XPITCH];

  const int wave = threadIdx.x >> 6, lane = threadIdx.x & 63;
  const int m = lane & 15, g = lane >> 4;
  const int c0w = wave * 48;

  bf16x8 wfrag[3][6];
#pragma unroll
  for (int ct = 0; ct < 3; ++ct)
#pragma unroll
    for (int ks = 0; ks < 6; ++ks)
      wfrag[ct][ks] = *(const bf16x8*)(pw + (size_t)(c0w + ct * 16 + m) * DIM + ks * 32 + g * 8);

  float4 b4[3];
#pragma unroll
  for (int ct = 0; ct < 3; ++ct)
    b4[ct] = *(const float4*)(pb + c0w + ct * 16 + g * 4);

  // staging coords: 256 thr = 32 rows x 8 groups of 24 shorts (bf16 copy)
  const int srow = threadIdx.x >> 3;
  const int scg  = threadIdx.x & 7;

  { // prologue: stage first tile into buf 0
    const short* sp = ain + ((size_t)(blockIdx.x * 32 + srow)) * DIM + scg * 24;
    short* dp = &as_[0][srow * XPITCH + scg * 24];
#pragma unroll
    for (int i = 0; i < 3; ++i)
      *(bf16x8*)(dp + i * 8) = *(const bf16x8*)(sp + i * 8);
  }
  __syncthreads();

  int cur = 0;
  for (int t = blockIdx.x; t < NTILE; t += PROJ_GRID) {
    const int tn = t + PROJ_GRID;
    const bool have = tn < NTILE;
    bf16x8 r0, r1, r2;
    if (have) {       // issue next-tile loads early
      const short* sp = ain + ((size_t)(tn * 32 + srow)) * DIM + scg * 24;
      r0 = *(const bf16x8*)(sp);
      r1 = *(const bf16x8*)(sp + 8);
      r2 = *(const bf16x8*)(sp + 16);
    }

    f32x4 acc[3][2];
#pragma unroll
    for (int ct = 0; ct < 3; ++ct)
#pragma unroll
      for (int rt = 0; rt < 2; ++rt) acc[ct][rt] = (f32x4){0.f, 0.f, 0.f, 0.f};

#pragma unroll
    for (int ks = 0; ks < 6; ++ks) {
      const short* bp_ = &as_[cur][m * XPITCH + ks * 32 + g * 8];
      bf16x8 b0 = *(const bf16x8*)bp_;
      bf16x8 b1 = *(const bf16x8*)(bp_ + 16 * XPITCH);
#pragma unroll
      for (int ct = 0; ct < 3; ++ct) {
        acc[ct][0] = __builtin_amdgcn_mfma_f32_16x16x32_bf16(wfrag[ct][ks], b0, acc[ct][0], 0, 0, 0);
        acc[ct][1] = __builtin_amdgcn_mfma_f32_16x16x32_bf16(wfrag[ct][ks], b1, acc[ct][1], 0, 0, 0);
      }
    }

#pragma unroll
    for (int ct = 0; ct < 3; ++ct) {
      int co0 = c0w + ct * 16 + g * 4;
#pragma unroll
      for (int rt = 0; rt < 2; ++rt) {
        int tok = t * 32 + rt * 16 + m;
        float4 o;
        o.x = acc[ct][rt][0] + b4[ct].x;
        o.y = acc[ct][rt][1] + b4[ct].y;
        o.z = acc[ct][rt][2] + b4[ct].z;
        o.w = acc[ct][rt][3] + b4[ct].w;
        *(float4*)(out + (size_t)tok * DIM + co0) = o;
      }
    }

    if (have) {       // write-late into other buffer
      short* dp = &as_[cur ^ 1][srow * XPITCH + scg * 24];
      *(bf16x8*)(dp)      = r0;
      *(bf16x8*)(dp + 8)  = r1;
      *(bf16x8*)(dp + 16) = r2;
    }
    __syncthreads();
    cur ^= 1;
  }
}

// ---------------------------------------------------------------------------
extern "C" void kernel_launch(void* const* d_in, const int* in_sizes, int n_in,
                              void* d_out, int out_size, void* d_ws, size_t ws_size,
                              hipStream_t stream) {
  const float* x          = (const float*)d_in[0];
  const float* mask       = (const float*)d_in[1];
  const float* qkv_w      = (const float*)d_in[2];
  const float* qkv_b      = (const float*)d_in[3];
  const float* proj_w     = (const float*)d_in[4];
  const float* proj_b     = (const float*)d_in[5];
  const float* bias_table = (const float*)d_in[6];
  const int*   pos_index  = (const int*)d_in[7];
  float* out = (float*)d_out;

  // workspace carve (16B-aligned)
  const size_t NELEM = (size_t)TOKENS * DIM;   // 26,542,080
  short* qv    = (short*)d_ws;
  short* kv    = qv + NELEM;
  short* vv    = kv + NELEM;
  short* aout  = vv + NELEM;
  short* wqb   = aout + NELEM;
  short* wpb   = wqb + NWQ;
  short* biasT = wpb + NWP;
  short* maskT = biasT + NBIAS;
  // total = 4*NELEM + NWQ + NWP + NBIAS + NMASK shorts ≈ 260.4 MB

  prep_kernel<<<(NB8 + NM8 + NWQ8 + NWP8 + 255) / 256, 256, 0, stream>>>(
      qkv_w, proj_w, bias_table, pos_index, mask, wqb, wpb, biasT, maskT);
  qkv_gemm<<<QKV_GRID, 768, 0, stream>>>(x, wqb, qkv_b, qv, kv, vv);
  attn_kernel<<<NBWH, 192, 0, stream>>>(qv, kv, vv, biasT, maskT, aout);
  proj_gemm<<<PROJ_GRID, 256, 0, stream>>>(aout, wpb, proj_b, out);
}

// Round 7
// 438.890 us; speedup vs baseline: 1.1148x; 1.0135x over previous
//
#include <hip/hip_runtime.h>
#include <hip/hip_bf16.h>

// EarthAttention3D (Pangu): B_=30, nW=32, N=144, C=192, H=6, hd=32
#define DIM    192
#define HEADS  6
#define HD     32
#define NTOK   144                  // tokens per window
#define NWIN   960                  // 30 lon * 32 window-types
#define NBWH   (NWIN * HEADS)       // 5760
#define TOKENS (NWIN * NTOK)        // 138240
#define PPITCH 168                  // attn LDS row pitch (halves)
#define XPITCH 200                  // gemm LDS x-tile pitch (halves): 100 dwords %32=4 -> 2-way max (free)
#define NTILE  (TOKENS / 32)        // 4320 token tiles
#define QKV_GRID  512
#define PROJ_GRID 1024
#define LOG2E  1.4426950408889634f  // softmax done in exp2 domain (v_exp_f32 is 2^x)

typedef __attribute__((ext_vector_type(8))) short bf16x8;   // MFMA A/B frag (4 VGPRs)
typedef __attribute__((ext_vector_type(4))) float f32x4;    // MFMA C/D frag
typedef __attribute__((ext_vector_type(4))) short short4v;  // 8 B vector store

static __device__ __forceinline__ short f2bf(float f) {
  __hip_bfloat16 h = __float2bfloat16(f);      // RTN
  return __builtin_bit_cast(short, h);
}
static __device__ __forceinline__ float bf2f(short s) {
  unsigned u = ((unsigned)(unsigned short)s) << 16;
  return __builtin_bit_cast(float, u);
}

// ---------------------------------------------------------------------------
// prep: bf16 weight casts + TILE-BLOCKED bias/mask expansion.
// biasT[wh][qtile][key][q16], maskT[bw][qtile][key][q16] (q16 = query within
// the 16-query rt tile): per (block, rt, jt) the attn wave reads 512
// CONTIGUOUS bytes, every fetched byte used once (R6: FETCH 413->214 MB =
// unique-traffic floor). bias/mask pre-scaled by LOG2E (exp2-domain softmax).
// ---------------------------------------------------------------------------
#define NBIAS (32 * HEADS * NTOK * NTOK)   // 3,981,312
#define NMASK (NWIN * NTOK * NTOK)         // 19,906,560
#define NWQ   (3 * DIM * DIM)              // 110,592
#define NWP   (DIM * DIM)                  // 36,864
#define NB8   (NBIAS / 8)
#define NM8   (NMASK / 8)
#define NWQ8  (NWQ / 8)
#define NWP8  (NWP / 8)

__global__ __launch_bounds__(256) void prep_kernel(
    const float* __restrict__ qkv_w, const float* __restrict__ proj_w,
    const float* __restrict__ bias_table, const int* __restrict__ pos_index,
    const float* __restrict__ mask,
    short* __restrict__ wq_b, short* __restrict__ wp_b,
    short* __restrict__ biasT, short* __restrict__ maskT)
{
  int i = blockIdx.x * 256 + threadIdx.x;
  if (i < NB8) {
    // one thread: 8 consecutive queries at fixed (w,h,key); q0 % 8 == 0 so
    // the 8 queries stay inside one 16-query tile half (q0%16 in {0,8}).
    int flat = i * 8;
    int q0 = flat % NTOK;
    int t  = flat / NTOK;
    int kk = t % NTOK;
    int t2 = t / NTOK;
    int h  = t2 % HEADS;
    int w  = t2 / HEADS;
    bf16x8 o;
#pragma unroll
    for (int jj = 0; jj < 8; ++jj) {
      int pos = pos_index[(q0 + jj) * NTOK + kk];
      o[jj] = f2bf(bias_table[(size_t)pos * (32 * HEADS) + w * HEADS + h] * LOG2E);
    }
    // [wh][q0/16][kk][q0%16]
    *(bf16x8*)(biasT + ((size_t)((w * HEADS + h) * 9 + (q0 >> 4)) * NTOK + kk) * 16 + (q0 & 15)) = o;
  } else if (i < NB8 + NM8) {
    int flat = (i - NB8) * 8;
    int q0 = flat % NTOK;
    int t  = flat / NTOK;
    int kk = t % NTOK;
    int bw = t / NTOK;
    bf16x8 o;
#pragma unroll
    for (int jj = 0; jj < 8; ++jj)
      o[jj] = f2bf(mask[((size_t)bw * NTOK + q0 + jj) * NTOK + kk] * LOG2E);
    // [bw][q0/16][kk][q0%16]
    *(bf16x8*)(maskT + ((size_t)(bw * 9 + (q0 >> 4)) * NTOK + kk) * 16 + (q0 & 15)) = o;
  } else if (i < NB8 + NM8 + NWQ8) {
    int flat = (i - NB8 - NM8) * 8;
    float4 f0 = *(const float4*)(qkv_w + flat);
    float4 f1 = *(const float4*)(qkv_w + flat + 4);
    bf16x8 o;
    o[0]=f2bf(f0.x); o[1]=f2bf(f0.y); o[2]=f2bf(f0.z); o[3]=f2bf(f0.w);
    o[4]=f2bf(f1.x); o[5]=f2bf(f1.y); o[6]=f2bf(f1.z); o[7]=f2bf(f1.w);
    *(bf16x8*)(wq_b + flat) = o;
  } else if (i < NB8 + NM8 + NWQ8 + NWP8) {
    int flat = (i - NB8 - NM8 - NWQ8) * 8;
    float4 f0 = *(const float4*)(proj_w + flat);
    float4 f1 = *(const float4*)(proj_w + flat + 4);
    bf16x8 o;
    o[0]=f2bf(f0.x); o[1]=f2bf(f0.y); o[2]=f2bf(f0.z); o[3]=f2bf(f0.w);
    o[4]=f2bf(f1.x); o[5]=f2bf(f1.y); o[6]=f2bf(f1.z); o[7]=f2bf(f1.w);
    *(bf16x8*)(wp_b + flat) = o;
  }
}

// ---------------------------------------------------------------------------
// QKV GEMM (R3): weights RESIDENT IN REGISTERS.
// Block = 768 thr (12 waves); wave owns 48 out-channels -> its full 48x192
// weight slice = 18 bf16x8 frags (72 VGPR), loaded ONCE. Grid-stride over
// 32-token tiles with double-buffered LDS x staging (load-early/write-late).
// dst (q/k/v) is wave-uniform: waves 0-3 -> q, 4-7 -> k, 8-11 -> v.
// q additionally folds scale = 32^-0.5 * LOG2E (exp2-domain softmax).
// ---------------------------------------------------------------------------
__global__ __launch_bounds__(768, 3) void qkv_gemm(
    const float* __restrict__ x, const short* __restrict__ wq,
    const float* __restrict__ qbias,
    short* __restrict__ q, short* __restrict__ k, short* __restrict__ v)
{
  __shared__ __align__(16) short xs[2][32 * XPITCH];

  const int wave = threadIdx.x >> 6, lane = threadIdx.x & 63;
  const int m = lane & 15, g = lane >> 4;
  const int c0w = wave * 48;

  // persistent weight fragments: 48 ch x 192 k per wave
  bf16x8 wfrag[3][6];
#pragma unroll
  for (int ct = 0; ct < 3; ++ct)
#pragma unroll
    for (int ks = 0; ks < 6; ++ks)
      wfrag[ct][ks] = *(const bf16x8*)(wq + (size_t)(c0w + ct * 16 + m) * DIM + ks * 32 + g * 8);

  const int which = wave >> 2;                  // 0=q 1=k 2=v (wave-uniform)
  short* dst = which == 0 ? q : (which == 1 ? k : v);
  const float sc = which == 0 ? (0.17677669529663689f * LOG2E) : 1.0f;

  float4 b4[3];
  int hh[3], d0[3];
#pragma unroll
  for (int ct = 0; ct < 3; ++ct) {
    int co0 = c0w + ct * 16 + g * 4;
    b4[ct] = *(const float4*)(qbias + co0);
    int rem = co0 - which * DIM;
    hh[ct] = rem >> 5; d0[ct] = rem & 31;
  }

  // staging coords: 768 thr = 32 rows x 24 col-groups of 8 floats
  const int srow = threadIdx.x / 24;
  const int scg  = threadIdx.x % 24;

  { // prologue: stage first tile into buf 0
    const float* xp = x + ((size_t)(blockIdx.x * 32 + srow)) * DIM + scg * 8;
    float4 f0 = ((const float4*)xp)[0];
    float4 f1 = ((const float4*)xp)[1];
    bf16x8 o;
    o[0]=f2bf(f0.x); o[1]=f2bf(f0.y); o[2]=f2bf(f0.z); o[3]=f2bf(f0.w);
    o[4]=f2bf(f1.x); o[5]=f2bf(f1.y); o[6]=f2bf(f1.z); o[7]=f2bf(f1.w);
    *(bf16x8*)(&xs[0][srow * XPITCH + scg * 8]) = o;
  }
  __syncthreads();

  int cur = 0;
  for (int t = blockIdx.x; t < NTILE; t += QKV_GRID) {
    const int tn = t + QKV_GRID;
    const bool have = tn < NTILE;
    float4 f0, f1;
    if (have) {       // issue next-tile loads EARLY (overlap with MFMA below)
      const float* xp = x + ((size_t)(tn * 32 + srow)) * DIM + scg * 8;
      f0 = ((const float4*)xp)[0];
      f1 = ((const float4*)xp)[1];
    }

    f32x4 acc[3][2];
#pragma unroll
    for (int ct = 0; ct < 3; ++ct)
#pragma unroll
      for (int rt = 0; rt < 2; ++rt) acc[ct][rt] = (f32x4){0.f, 0.f, 0.f, 0.f};

#pragma unroll
    for (int ks = 0; ks < 6; ++ks) {
      const short* bp_ = &xs[cur][m * XPITCH + ks * 32 + g * 8];
      bf16x8 b0 = *(const bf16x8*)bp_;
      bf16x8 b1 = *(const bf16x8*)(bp_ + 16 * XPITCH);
#pragma unroll
      for (int ct = 0; ct < 3; ++ct) {
        acc[ct][0] = __builtin_amdgcn_mfma_f32_16x16x32_bf16(wfrag[ct][ks], b0, acc[ct][0], 0, 0, 0);
        acc[ct][1] = __builtin_amdgcn_mfma_f32_16x16x32_bf16(wfrag[ct][ks], b1, acc[ct][1], 0, 0, 0);
      }
    }

#pragma unroll
    for (int ct = 0; ct < 3; ++ct) {
#pragma unroll
      for (int rt = 0; rt < 2; ++rt) {
        int tok = t * 32 + rt * 16 + m;
        int bw = tok / NTOK, n = tok - bw * NTOK;
        short4v s;
        s[0] = f2bf((acc[ct][rt][0] + b4[ct].x) * sc);
        s[1] = f2bf((acc[ct][rt][1] + b4[ct].y) * sc);
        s[2] = f2bf((acc[ct][rt][2] + b4[ct].z) * sc);
        s[3] = f2bf((acc[ct][rt][3] + b4[ct].w) * sc);
        *(short4v*)(dst + ((size_t)(bw * HEADS + hh[ct]) * NTOK + n) * HD + d0[ct]) = s;
      }
    }

    if (have) {       // write-late: cvt + ds_write into the other buffer
      bf16x8 o;
      o[0]=f2bf(f0.x); o[1]=f2bf(f0.y); o[2]=f2bf(f0.z); o[3]=f2bf(f0.w);
      o[4]=f2bf(f1.x); o[5]=f2bf(f1.y); o[6]=f2bf(f1.z); o[7]=f2bf(f1.w);
      *(bf16x8*)(&xs[cur ^ 1][srow * XPITCH + scg * 8]) = o;
    }
    __syncthreads();
    cur ^= 1;
  }
}

// ---------------------------------------------------------------------------
// Attention (R7): chain-shortened softmax.
//  - bias+mask preloaded into the MFMA C-operand (adds off the critical path)
//  - NO row-max: scores bounded (|s| << 100) so exp2 direct is exact-safe;
//    removes fmax + subtract + 16 cross-lane max shuffles per rt
//  - deferred normalization: P stored unnormalized, o *= 1/sum after PV;
//    1/sum crosses (g,r)->m lane mapping via 3 cndmask + 1 shfl
//  - K staged in LDS (linear [n][d], conflict-floor reads) -> no 9x global
//    K re-reads per rt; Q stays global (read once per rt)
// XCD-grouping swizzle kept (same-XCD mask sharing). Occupancy: LDS 36.1 KB
// -> 4 blocks/CU max, >= measured 3.
// ---------------------------------------------------------------------------
__global__ __launch_bounds__(192, 3) void attn_kernel(
    const short* __restrict__ q, const short* __restrict__ k,
    const short* __restrict__ v, const short* __restrict__ biasT,
    const short* __restrict__ maskT, short* __restrict__ aout)
{
  const int b    = blockIdx.x;
  const int xcd  = b & 7;
  const int slot = b >> 3;                   // 0..719
  const int bw   = xcd * 120 + slot / 6;     // 6 heads of one bw share an XCD
  const int h    = slot % 6;
  const int bwh  = bw * HEADS + h;
  const int w    = bw & 31;                  // window-type; lon = bw>>5

  __shared__ __align__(16) short kls[NTOK * HD];        // k linear [n][d]
  __shared__ __align__(16) short vt[HD * PPITCH];       // v transposed [d][n]
  __shared__ __align__(16) short pl[3 * 16 * PPITCH];   // per-wave P tile

  const size_t base = (size_t)bwh * (NTOK * HD);
  const short* qb = q + base;
  const short* kb = k + base;
  const short* vb = v + base;

  // stage K (straight copy) + V (transpose) -> LDS
  for (int i = threadIdx.x; i < (NTOK * HD) / 8; i += 192) {
    *(bf16x8*)(kls + i * 8) = *(const bf16x8*)(kb + i * 8);
    int n = i >> 2, dg = (i & 3) * 8;
    bf16x8 vv = *(const bf16x8*)(vb + n * HD + dg);
#pragma unroll
    for (int j = 0; j < 8; ++j) vt[(dg + j) * PPITCH + n] = vv[j];
  }
  // zero K-pad cols 144..160 of vt
  for (int i = threadIdx.x; i < 128; i += 192) {
    int d = i >> 2, c = 144 + (i & 3) * 4;
    *(short4v*)&vt[d * PPITCH + c] = (short4v){0, 0, 0, 0};
  }
  __syncthreads();

  const int wv = threadIdx.x >> 6;
  const int lane = threadIdx.x & 63;
  const int m = lane & 15, g = lane >> 4;
  short* myp = pl + wv * 16 * PPITCH;
  { // zero K-pad of own wave's P rows
    int r = lane >> 2, c = 144 + (lane & 3) * 4;
    *(short4v*)&myp[r * PPITCH + c] = (short4v){0, 0, 0, 0};
  }

  // tile-blocked tables: [wh][rt][key][q16] / [bw][rt][key][q16]
  const short* bp = biasT + (size_t)(w * HEADS + h) * (9 * NTOK * 16);
  const short* mp = maskT + (size_t)bw * (9 * NTOK * 16);

  for (int rt = wv * 3; rt < wv * 3 + 3; ++rt) {
    const int i0 = rt * 16;
    const short* bpt = bp + rt * (NTOK * 16);
    const short* mpt = mp + rt * (NTOK * 16);
    bf16x8 aq = *(const bf16x8*)(qb + (size_t)(i0 + m) * HD + g * 8);
    f32x4 s[9];
#pragma unroll
    for (int jt = 0; jt < 9; ++jt) {
      const int key = jt * 16 + m;
      short4v bb = *(const short4v*)(bpt + key * 16 + g * 4);
      short4v mm = *(const short4v*)(mpt + key * 16 + g * 4);
      f32x4 cini;
#pragma unroll
      for (int r = 0; r < 4; ++r) cini[r] = bf2f(bb[r]) + bf2f(mm[r]);
      bf16x8 bk = *(const bf16x8*)(kls + key * HD + g * 8);
      s[jt] = __builtin_amdgcn_mfma_f32_16x16x32_bf16(aq, bk, cini, 0, 0, 0);
    }
    // exp2 (no max: scores bounded, exp2-domain pre-folded) + row sums
    float sum[4] = {0.f, 0.f, 0.f, 0.f};
#pragma unroll
    for (int jt = 0; jt < 9; ++jt) {
#pragma unroll
      for (int r = 0; r < 4; ++r) {
        float e = __builtin_amdgcn_exp2f(s[jt][r]);
        s[jt][r] = e;
        sum[r] += e;
      }
    }
#pragma unroll
    for (int r = 0; r < 4; ++r) {
      sum[r] += __shfl_xor(sum[r], 1, 64);
      sum[r] += __shfl_xor(sum[r], 2, 64);
      sum[r] += __shfl_xor(sum[r], 4, 64);
      sum[r] += __shfl_xor(sum[r], 8, 64);
    }
    float rs[4];
#pragma unroll
    for (int r = 0; r < 4; ++r) rs[r] = 1.0f / sum[r];
    // unnormalized P -> LDS bf16 (norm deferred to output)
#pragma unroll
    for (int jt = 0; jt < 9; ++jt)
#pragma unroll
      for (int r = 0; r < 4; ++r)
        myp[(g * 4 + r) * PPITCH + jt * 16 + m] = f2bf(s[jt][r]);

    // cross-map 1/sum from (g,r) layout to m layout: lane m needs rs of
    // query m, held as rs[m&3] on any lane with g==m>>2.
    float xs0 = (lane & 1) ? rs[1] : rs[0];
    float xs1 = (lane & 1) ? rs[3] : rs[2];
    float xsel = (lane & 2) ? xs1 : xs0;
    float rv = __shfl(xsel, ((m >> 2) << 4) | (m & 3), 64);

    // O^T = V^T @ P^T (operand-swapped): D rows = d-channels, cols = queries.
    f32x4 o0 = (f32x4){0.f, 0.f, 0.f, 0.f};
    f32x4 o1 = (f32x4){0.f, 0.f, 0.f, 0.f};
#pragma unroll
    for (int kt = 0; kt < 5; ++kt) {
      bf16x8 ap = *(const bf16x8*)(myp + m * PPITCH + kt * 32 + g * 8);
      bf16x8 b0 = *(const bf16x8*)(vt + m * PPITCH + kt * 32 + g * 8);
      bf16x8 b1 = *(const bf16x8*)(vt + (16 + m) * PPITCH + kt * 32 + g * 8);
      o0 = __builtin_amdgcn_mfma_f32_16x16x32_bf16(b0, ap, o0, 0, 0, 0);
      o1 = __builtin_amdgcn_mfma_f32_16x16x32_bf16(b1, ap, o1, 0, 0, 0);
    }
    // lane: token = i0+m, d = g*4+r (o0) / 16+g*4+r (o1) -> two short4 stores
    size_t ob = ((size_t)(bw * NTOK + i0 + m)) * DIM + h * HD + g * 4;
    short4v s0, s1;
#pragma unroll
    for (int r = 0; r < 4; ++r) { s0[r] = f2bf(o0[r] * rv); s1[r] = f2bf(o1[r] * rv); }
    *(short4v*)(aout + ob) = s0;
    *(short4v*)(aout + ob + 16) = s1;
  }
}

// ---------------------------------------------------------------------------
// Proj GEMM (R3): same template as qkv_gemm. Block = 256 thr
// (4 waves x 48 ch = 192 out-ch); wave's 48x192 weight slice resident in
// registers (18 frags); grid-stride over 32-token tiles, double-buffered LDS
// ain staging with load-early/write-late. Lane stores float4 (16 B).
// ---------------------------------------------------------------------------
__global__ __launch_bounds__(256, 3) void proj_gemm(
    const short* __restrict__ ain, const short* __restrict__ pw,
    const float* __restrict__ pb, float* __restrict__ out)
{
  __shared__ __align__(16) short as_[2][32 * XPITCH];

  const int wave = threadIdx.x >> 6, lane = threadIdx.x & 63;
  const int m = lane & 15, g = lane >> 4;
  const int c0w = wave * 48;

  bf16x8 wfrag[3][6];
#pragma unroll
  for (int ct = 0; ct < 3; ++ct)
#pragma unroll
    for (int ks = 0; ks < 6; ++ks)
      wfrag[ct][ks] = *(const bf16x8*)(pw + (size_t)(c0w + ct * 16 + m) * DIM + ks * 32 + g * 8);

  float4 b4[3];
#pragma unroll
  for (int ct = 0; ct < 3; ++ct)
    b4[ct] = *(const float4*)(pb + c0w + ct * 16 + g * 4);

  // staging coords: 256 thr = 32 rows x 8 groups of 24 shorts (bf16 copy)
  const int srow = threadIdx.x >> 3;
  const int scg  = threadIdx.x & 7;

  { // prologue: stage first tile into buf 0
    const short* sp = ain + ((size_t)(blockIdx.x * 32 + srow)) * DIM + scg * 24;
    short* dp = &as_[0][srow * XPITCH + scg * 24];
#pragma unroll
    for (int i = 0; i < 3; ++i)
      *(bf16x8*)(dp + i * 8) = *(const bf16x8*)(sp + i * 8);
  }
  __syncthreads();

  int cur = 0;
  for (int t = blockIdx.x; t < NTILE; t += PROJ_GRID) {
    const int tn = t + PROJ_GRID;
    const bool have = tn < NTILE;
    bf16x8 r0, r1, r2;
    if (have) {       // issue next-tile loads early
      const short* sp = ain + ((size_t)(tn * 32 + srow)) * DIM + scg * 24;
      r0 = *(const bf16x8*)(sp);
      r1 = *(const bf16x8*)(sp + 8);
      r2 = *(const bf16x8*)(sp + 16);
    }

    f32x4 acc[3][2];
#pragma unroll
    for (int ct = 0; ct < 3; ++ct)
#pragma unroll
      for (int rt = 0; rt < 2; ++rt) acc[ct][rt] = (f32x4){0.f, 0.f, 0.f, 0.f};

#pragma unroll
    for (int ks = 0; ks < 6; ++ks) {
      const short* bp_ = &as_[cur][m * XPITCH + ks * 32 + g * 8];
      bf16x8 b0 = *(const bf16x8*)bp_;
      bf16x8 b1 = *(const bf16x8*)(bp_ + 16 * XPITCH);
#pragma unroll
      for (int ct = 0; ct < 3; ++ct) {
        acc[ct][0] = __builtin_amdgcn_mfma_f32_16x16x32_bf16(wfrag[ct][ks], b0, acc[ct][0], 0, 0, 0);
        acc[ct][1] = __builtin_amdgcn_mfma_f32_16x16x32_bf16(wfrag[ct][ks], b1, acc[ct][1], 0, 0, 0);
      }
    }

#pragma unroll
    for (int ct = 0; ct < 3; ++ct) {
      int co0 = c0w + ct * 16 + g * 4;
#pragma unroll
      for (int rt = 0; rt < 2; ++rt) {
        int tok = t * 32 + rt * 16 + m;
        float4 o;
        o.x = acc[ct][rt][0] + b4[ct].x;
        o.y = acc[ct][rt][1] + b4[ct].y;
        o.z = acc[ct][rt][2] + b4[ct].z;
        o.w = acc[ct][rt][3] + b4[ct].w;
        *(float4*)(out + (size_t)tok * DIM + co0) = o;
      }
    }

    if (have) {       // write-late into other buffer
      short* dp = &as_[cur ^ 1][srow * XPITCH + scg * 24];
      *(bf16x8*)(dp)      = r0;
      *(bf16x8*)(dp + 8)  = r1;
      *(bf16x8*)(dp + 16) = r2;
    }
    __syncthreads();
    cur ^= 1;
  }
}

// ---------------------------------------------------------------------------
extern "C" void kernel_launch(void* const* d_in, const int* in_sizes, int n_in,
                              void* d_out, int out_size, void* d_ws, size_t ws_size,
                              hipStream_t stream) {
  const float* x          = (const float*)d_in[0];
  const float* mask       = (const float*)d_in[1];
  const float* qkv_w      = (const float*)d_in[2];
  const float* qkv_b      = (const float*)d_in[3];
  const float* proj_w     = (const float*)d_in[4];
  const float* proj_b     = (const float*)d_in[5];
  const float* bias_table = (const float*)d_in[6];
  const int*   pos_index  = (const int*)d_in[7];
  float* out = (float*)d_out;

  // workspace carve (16B-aligned)
  const size_t NELEM = (size_t)TOKENS * DIM;   // 26,542,080
  short* qv    = (short*)d_ws;
  short* kv    = qv + NELEM;
  short* vv    = kv + NELEM;
  short* aout  = vv + NELEM;
  short* wqb   = aout + NELEM;
  short* wpb   = wqb + NWQ;
  short* biasT = wpb + NWP;
  short* maskT = biasT + NBIAS;
  // total = 4*NELEM + NWQ + NWP + NBIAS + NMASK shorts ≈ 260.4 MB

  prep_kernel<<<(NB8 + NM8 + NWQ8 + NWP8 + 255) / 256, 256, 0, stream>>>(
      qkv_w, proj_w, bias_table, pos_index, mask, wqb, wpb, biasT, maskT);
  qkv_gemm<<<QKV_GRID, 768, 0, stream>>>(x, wqb, qkv_b, qv, kv, vv);
  attn_kernel<<<NBWH, 192, 0, stream>>>(qv, kv, vv, biasT, maskT, aout);
  proj_gemm<<<PROJ_GRID, 256, 0, stream>>>(aout, wpb, proj_b, out);
}

// Round 9
// 431.552 us; speedup vs baseline: 1.1338x; 1.0170x over previous
//
#include <hip/hip_runtime.h>
#include <hip/hip_bf16.h>

// EarthAttention3D (Pangu): B_=30, nW=32, N=144, C=192, H=6, hd=32
#define DIM    192
#define HEADS  6
#define HD     32
#define NTOK   144                  // tokens per window
#define NWIN   960                  // 30 lon * 32 window-types
#define NBWH   (NWIN * HEADS)       // 5760
#define TOKENS (NWIN * NTOK)        // 138240
#define PPITCH 168                  // attn LDS row pitch (halves)
#define XPITCH 200                  // gemm LDS x-tile pitch (halves): 100 dwords %32=4 -> 2-way max (free)
#define NTILE  (TOKENS / 32)        // 4320 token tiles
#define QKV_GRID  512
#define PROJ_GRID 1024
#define LOG2E  1.4426950408889634f  // softmax done in exp2 domain (v_exp_f32 is 2^x)

typedef __attribute__((ext_vector_type(8))) short bf16x8;   // MFMA A/B frag (4 VGPRs)
typedef __attribute__((ext_vector_type(4))) float f32x4;    // MFMA C/D frag
typedef __attribute__((ext_vector_type(4))) short short4v;  // 8 B vector store

static __device__ __forceinline__ short f2bf(float f) {
  __hip_bfloat16 h = __float2bfloat16(f);      // RTN
  return __builtin_bit_cast(short, h);
}
static __device__ __forceinline__ float bf2f(short s) {
  unsigned u = ((unsigned)(unsigned short)s) << 16;
  return __builtin_bit_cast(float, u);
}

// ---------------------------------------------------------------------------
// prep (R9 = R8 + grid fix): LDS-TILE TRANSPOSE.
//  - blocks [0,960): mask bw-slice — coalesced float4 read along k, bf16 to
//    LDS tile [q][k] (pitch 148), then fully-coalesced bf16x8 writes of
//    maskT[bw][qt][k][q16].
//  - blocks [960,1152): bias wh-slice, wh = w*6+h in [0,192)  <-- R8 BUG was
//    576 blocks: slices 192-575 overflowed biasT (192*20736 shorts) into
//    maskT and read wrong bias_table entries. 192 slices is the whole table.
//  - blocks [1152,1224): weight casts (unchanged logic).
// Output layouts identical to R6/R7 (attn unchanged).
// ---------------------------------------------------------------------------
#define NBIAS (32 * HEADS * NTOK * NTOK)   // 3,981,312 = 192 slices * 20736
#define NMASK (NWIN * NTOK * NTOK)         // 19,906,560
#define NWQ   (3 * DIM * DIM)              // 110,592
#define NWP   (DIM * DIM)                  // 36,864
#define NWQ8  (NWQ / 8)
#define NWP8  (NWP / 8)
#define PRPITCH 148                        // prep LDS tile pitch (halves)
#define NWH   (32 * HEADS)                 // 192 bias slices
#define PREP_GRID (NWIN + NWH + 72)        // 960 mask + 192 bias + 72 weights

__global__ __launch_bounds__(256) void prep_kernel(
    const float* __restrict__ qkv_w, const float* __restrict__ proj_w,
    const float* __restrict__ bias_table, const int* __restrict__ pos_index,
    const float* __restrict__ mask,
    short* __restrict__ wq_b, short* __restrict__ wp_b,
    short* __restrict__ biasT, short* __restrict__ maskT)
{
  __shared__ __align__(16) short tile[NTOK * PRPITCH];   // 42.6 KB
  const int blk = blockIdx.x;
  const int t   = threadIdx.x;

  if (blk < NWIN) {
    // ---- mask transpose for bw = blk ----
    const int bw = blk;
    const float* mrow = mask + (size_t)bw * NTOK * NTOK;   // [q][k] fp32
    for (int idx = t; idx < (NTOK * NTOK) / 4; idx += 256) {
      int qq = idx / (NTOK / 4);
      int k4 = (idx - qq * (NTOK / 4)) * 4;
      float4 f = *(const float4*)(mrow + qq * NTOK + k4);
      short4v o4;
      o4[0] = f2bf(f.x * LOG2E); o4[1] = f2bf(f.y * LOG2E);
      o4[2] = f2bf(f.z * LOG2E); o4[3] = f2bf(f.w * LOG2E);
      *(short4v*)(tile + qq * PRPITCH + k4) = o4;
    }
    __syncthreads();
    short* outp = maskT + (size_t)bw * (9 * NTOK * 16);
    for (int c = t; c < 9 * NTOK * 2; c += 256) {   // (qt,k,q8) chunks of 8
      int q8  = c & 1;
      int kqt = c >> 1;
      int k   = kqt % NTOK;
      int qt  = kqt / NTOK;
      int q0  = qt * 16 + q8 * 8;
      bf16x8 o;
#pragma unroll
      for (int j = 0; j < 8; ++j) o[j] = tile[(q0 + j) * PRPITCH + k];
      *(bf16x8*)(outp + c * 8) = o;
    }
  } else if (blk < NWIN + NWH) {
    // ---- bias build for wh = w*6+h, wh in [0,192) ----
    const int wh = blk - NWIN;
    for (int idx = t; idx < (NTOK * NTOK) / 4; idx += 256) {
      int qq = idx / (NTOK / 4);
      int k4 = (idx - qq * (NTOK / 4)) * 4;
      int4 p = *(const int4*)(pos_index + qq * NTOK + k4);   // coalesced
      short4v o4;
      o4[0] = f2bf(bias_table[(size_t)p.x * NWH + wh] * LOG2E);
      o4[1] = f2bf(bias_table[(size_t)p.y * NWH + wh] * LOG2E);
      o4[2] = f2bf(bias_table[(size_t)p.z * NWH + wh] * LOG2E);
      o4[3] = f2bf(bias_table[(size_t)p.w * NWH + wh] * LOG2E);
      *(short4v*)(tile + qq * PRPITCH + k4) = o4;
    }
    __syncthreads();
    short* outp = biasT + (size_t)wh * (9 * NTOK * 16);
    for (int c = t; c < 9 * NTOK * 2; c += 256) {
      int q8  = c & 1;
      int kqt = c >> 1;
      int k   = kqt % NTOK;
      int qt  = kqt / NTOK;
      int q0  = qt * 16 + q8 * 8;
      bf16x8 o;
#pragma unroll
      for (int j = 0; j < 8; ++j) o[j] = tile[(q0 + j) * PRPITCH + k];
      *(bf16x8*)(outp + c * 8) = o;
    }
  } else {
    // ---- weight casts ----
    int j = (blk - NWIN - NWH) * 256 + t;
    if (j < NWQ8) {
      int flat = j * 8;
      float4 f0 = *(const float4*)(qkv_w + flat);
      float4 f1 = *(const float4*)(qkv_w + flat + 4);
      bf16x8 o;
      o[0]=f2bf(f0.x); o[1]=f2bf(f0.y); o[2]=f2bf(f0.z); o[3]=f2bf(f0.w);
      o[4]=f2bf(f1.x); o[5]=f2bf(f1.y); o[6]=f2bf(f1.z); o[7]=f2bf(f1.w);
      *(bf16x8*)(wq_b + flat) = o;
    } else if (j < NWQ8 + NWP8) {
      int flat = (j - NWQ8) * 8;
      float4 f0 = *(const float4*)(proj_w + flat);
      float4 f1 = *(const float4*)(proj_w + flat + 4);
      bf16x8 o;
      o[0]=f2bf(f0.x); o[1]=f2bf(f0.y); o[2]=f2bf(f0.z); o[3]=f2bf(f0.w);
      o[4]=f2bf(f1.x); o[5]=f2bf(f1.y); o[6]=f2bf(f1.z); o[7]=f2bf(f1.w);
      *(bf16x8*)(wp_b + flat) = o;
    }
  }
}

// ---------------------------------------------------------------------------
// QKV GEMM (R3): weights RESIDENT IN REGISTERS.
// Block = 768 thr (12 waves); wave owns 48 out-channels -> its full 48x192
// weight slice = 18 bf16x8 frags (72 VGPR), loaded ONCE. Grid-stride over
// 32-token tiles with double-buffered LDS x staging (load-early/write-late).
// dst (q/k/v) is wave-uniform: waves 0-3 -> q, 4-7 -> k, 8-11 -> v.
// q additionally folds scale = 32^-0.5 * LOG2E (exp2-domain softmax).
// ---------------------------------------------------------------------------
__global__ __launch_bounds__(768, 3) void qkv_gemm(
    const float* __restrict__ x, const short* __restrict__ wq,
    const float* __restrict__ qbias,
    short* __restrict__ q, short* __restrict__ k, short* __restrict__ v)
{
  __shared__ __align__(16) short xs[2][32 * XPITCH];

  const int wave = threadIdx.x >> 6, lane = threadIdx.x & 63;
  const int m = lane & 15, g = lane >> 4;
  const int c0w = wave * 48;

  // persistent weight fragments: 48 ch x 192 k per wave
  bf16x8 wfrag[3][6];
#pragma unroll
  for (int ct = 0; ct < 3; ++ct)
#pragma unroll
    for (int ks = 0; ks < 6; ++ks)
      wfrag[ct][ks] = *(const bf16x8*)(wq + (size_t)(c0w + ct * 16 + m) * DIM + ks * 32 + g * 8);

  const int which = wave >> 2;                  // 0=q 1=k 2=v (wave-uniform)
  short* dst = which == 0 ? q : (which == 1 ? k : v);
  const float sc = which == 0 ? (0.17677669529663689f * LOG2E) : 1.0f;

  float4 b4[3];
  int hh[3], d0[3];
#pragma unroll
  for (int ct = 0; ct < 3; ++ct) {
    int co0 = c0w + ct * 16 + g * 4;
    b4[ct] = *(const float4*)(qbias + co0);
    int rem = co0 - which * DIM;
    hh[ct] = rem >> 5; d0[ct] = rem & 31;
  }

  // staging coords: 768 thr = 32 rows x 24 col-groups of 8 floats
  const int srow = threadIdx.x / 24;
  const int scg  = threadIdx.x % 24;

  { // prologue: stage first tile into buf 0
    const float* xp = x + ((size_t)(blockIdx.x * 32 + srow)) * DIM + scg * 8;
    float4 f0 = ((const float4*)xp)[0];
    float4 f1 = ((const float4*)xp)[1];
    bf16x8 o;
    o[0]=f2bf(f0.x); o[1]=f2bf(f0.y); o[2]=f2bf(f0.z); o[3]=f2bf(f0.w);
    o[4]=f2bf(f1.x); o[5]=f2bf(f1.y); o[6]=f2bf(f1.z); o[7]=f2bf(f1.w);
    *(bf16x8*)(&xs[0][srow * XPITCH + scg * 8]) = o;
  }
  __syncthreads();

  int cur = 0;
  for (int t = blockIdx.x; t < NTILE; t += QKV_GRID) {
    const int tn = t + QKV_GRID;
    const bool have = tn < NTILE;
    float4 f0, f1;
    if (have) {       // issue next-tile loads EARLY (overlap with MFMA below)
      const float* xp = x + ((size_t)(tn * 32 + srow)) * DIM + scg * 8;
      f0 = ((const float4*)xp)[0];
      f1 = ((const float4*)xp)[1];
    }

    f32x4 acc[3][2];
#pragma unroll
    for (int ct = 0; ct < 3; ++ct)
#pragma unroll
      for (int rt = 0; rt < 2; ++rt) acc[ct][rt] = (f32x4){0.f, 0.f, 0.f, 0.f};

#pragma unroll
    for (int ks = 0; ks < 6; ++ks) {
      const short* bp_ = &xs[cur][m * XPITCH + ks * 32 + g * 8];
      bf16x8 b0 = *(const bf16x8*)bp_;
      bf16x8 b1 = *(const bf16x8*)(bp_ + 16 * XPITCH);
#pragma unroll
      for (int ct = 0; ct < 3; ++ct) {
        acc[ct][0] = __builtin_amdgcn_mfma_f32_16x16x32_bf16(wfrag[ct][ks], b0, acc[ct][0], 0, 0, 0);
        acc[ct][1] = __builtin_amdgcn_mfma_f32_16x16x32_bf16(wfrag[ct][ks], b1, acc[ct][1], 0, 0, 0);
      }
    }

#pragma unroll
    for (int ct = 0; ct < 3; ++ct) {
#pragma unroll
      for (int rt = 0; rt < 2; ++rt) {
        int tok = t * 32 + rt * 16 + m;
        int bw = tok / NTOK, n = tok - bw * NTOK;
        short4v s;
        s[0] = f2bf((acc[ct][rt][0] + b4[ct].x) * sc);
        s[1] = f2bf((acc[ct][rt][1] + b4[ct].y) * sc);
        s[2] = f2bf((acc[ct][rt][2] + b4[ct].z) * sc);
        s[3] = f2bf((acc[ct][rt][3] + b4[ct].w) * sc);
        *(short4v*)(dst + ((size_t)(bw * HEADS + hh[ct]) * NTOK + n) * HD + d0[ct]) = s;
      }
    }

    if (have) {       // write-late: cvt + ds_write into the other buffer
      bf16x8 o;
      o[0]=f2bf(f0.x); o[1]=f2bf(f0.y); o[2]=f2bf(f0.z); o[3]=f2bf(f0.w);
      o[4]=f2bf(f1.x); o[5]=f2bf(f1.y); o[6]=f2bf(f1.z); o[7]=f2bf(f1.w);
      *(bf16x8*)(&xs[cur ^ 1][srow * XPITCH + scg * 8]) = o;
    }
    __syncthreads();
    cur ^= 1;
  }
}

// ---------------------------------------------------------------------------
// Attention (R7, unchanged): chain-shortened softmax.
//  - bias+mask preloaded into the MFMA C-operand
//  - no row-max (scores bounded; exp2-domain pre-folded)
//  - deferred normalization (o *= 1/sum after PV)
//  - K staged in LDS; XCD-grouping swizzle kept
// ---------------------------------------------------------------------------
__global__ __launch_bounds__(192, 3) void attn_kernel(
    const short* __restrict__ q, const short* __restrict__ k,
    const short* __restrict__ v, const short* __restrict__ biasT,
    const short* __restrict__ maskT, short* __restrict__ aout)
{
  const int b    = blockIdx.x;
  const int xcd  = b & 7;
  const int slot = b >> 3;                   // 0..719
  const int bw   = xcd * 120 + slot / 6;     // 6 heads of one bw share an XCD
  const int h    = slot % 6;
  const int bwh  = bw * HEADS + h;
  const int w    = bw & 31;                  // window-type; lon = bw>>5

  __shared__ __align__(16) short kls[NTOK * HD];        // k linear [n][d]
  __shared__ __align__(16) short vt[HD * PPITCH];       // v transposed [d][n]
  __shared__ __align__(16) short pl[3 * 16 * PPITCH];   // per-wave P tile

  const size_t base = (size_t)bwh * (NTOK * HD);
  const short* qb = q + base;
  const short* kb = k + base;
  const short* vb = v + base;

  // stage K (straight copy) + V (transpose) -> LDS
  for (int i = threadIdx.x; i < (NTOK * HD) / 8; i += 192) {
    *(bf16x8*)(kls + i * 8) = *(const bf16x8*)(kb + i * 8);
    int n = i >> 2, dg = (i & 3) * 8;
    bf16x8 vv = *(const bf16x8*)(vb + n * HD + dg);
#pragma unroll
    for (int j = 0; j < 8; ++j) vt[(dg + j) * PPITCH + n] = vv[j];
  }
  // zero K-pad cols 144..160 of vt
  for (int i = threadIdx.x; i < 128; i += 192) {
    int d = i >> 2, c = 144 + (i & 3) * 4;
    *(short4v*)&vt[d * PPITCH + c] = (short4v){0, 0, 0, 0};
  }
  __syncthreads();

  const int wv = threadIdx.x >> 6;
  const int lane = threadIdx.x & 63;
  const int m = lane & 15, g = lane >> 4;
  short* myp = pl + wv * 16 * PPITCH;
  { // zero K-pad of own wave's P rows
    int r = lane >> 2, c = 144 + (lane & 3) * 4;
    *(short4v*)&myp[r * PPITCH + c] = (short4v){0, 0, 0, 0};
  }

  // tile-blocked tables: [wh][rt][key][q16] / [bw][rt][key][q16]
  const short* bp = biasT + (size_t)(w * HEADS + h) * (9 * NTOK * 16);
  const short* mp = maskT + (size_t)bw * (9 * NTOK * 16);

  for (int rt = wv * 3; rt < wv * 3 + 3; ++rt) {
    const int i0 = rt * 16;
    const short* bpt = bp + rt * (NTOK * 16);
    const short* mpt = mp + rt * (NTOK * 16);
    bf16x8 aq = *(const bf16x8*)(qb + (size_t)(i0 + m) * HD + g * 8);
    f32x4 s[9];
#pragma unroll
    for (int jt = 0; jt < 9; ++jt) {
      const int key = jt * 16 + m;
      short4v bb = *(const short4v*)(bpt + key * 16 + g * 4);
      short4v mm = *(const short4v*)(mpt + key * 16 + g * 4);
      f32x4 cini;
#pragma unroll
      for (int r = 0; r < 4; ++r) cini[r] = bf2f(bb[r]) + bf2f(mm[r]);
      bf16x8 bk = *(const bf16x8*)(kls + key * HD + g * 8);
      s[jt] = __builtin_amdgcn_mfma_f32_16x16x32_bf16(aq, bk, cini, 0, 0, 0);
    }
    // exp2 (no max: scores bounded, exp2-domain pre-folded) + row sums
    float sum[4] = {0.f, 0.f, 0.f, 0.f};
#pragma unroll
    for (int jt = 0; jt < 9; ++jt) {
#pragma unroll
      for (int r = 0; r < 4; ++r) {
        float e = __builtin_amdgcn_exp2f(s[jt][r]);
        s[jt][r] = e;
        sum[r] += e;
      }
    }
#pragma unroll
    for (int r = 0; r < 4; ++r) {
      sum[r] += __shfl_xor(sum[r], 1, 64);
      sum[r] += __shfl_xor(sum[r], 2, 64);
      sum[r] += __shfl_xor(sum[r], 4, 64);
      sum[r] += __shfl_xor(sum[r], 8, 64);
    }
    float rs[4];
#pragma unroll
    for (int r = 0; r < 4; ++r) rs[r] = 1.0f / sum[r];
    // unnormalized P -> LDS bf16 (norm deferred to output)
#pragma unroll
    for (int jt = 0; jt < 9; ++jt)
#pragma unroll
      for (int r = 0; r < 4; ++r)
        myp[(g * 4 + r) * PPITCH + jt * 16 + m] = f2bf(s[jt][r]);

    // cross-map 1/sum from (g,r) layout to m layout: lane m needs rs of
    // query m, held as rs[m&3] on any lane with g==m>>2.
    float xs0 = (lane & 1) ? rs[1] : rs[0];
    float xs1 = (lane & 1) ? rs[3] : rs[2];
    float xsel = (lane & 2) ? xs1 : xs0;
    float rv = __shfl(xsel, ((m >> 2) << 4) | (m & 3), 64);

    // O^T = V^T @ P^T (operand-swapped): D rows = d-channels, cols = queries.
    f32x4 o0 = (f32x4){0.f, 0.f, 0.f, 0.f};
    f32x4 o1 = (f32x4){0.f, 0.f, 0.f, 0.f};
#pragma unroll
    for (int kt = 0; kt < 5; ++kt) {
      bf16x8 ap = *(const bf16x8*)(myp + m * PPITCH + kt * 32 + g * 8);
      bf16x8 b0 = *(const bf16x8*)(vt + m * PPITCH + kt * 32 + g * 8);
      bf16x8 b1 = *(const bf16x8*)(vt + (16 + m) * PPITCH + kt * 32 + g * 8);
      o0 = __builtin_amdgcn_mfma_f32_16x16x32_bf16(b0, ap, o0, 0, 0, 0);
      o1 = __builtin_amdgcn_mfma_f32_16x16x32_bf16(b1, ap, o1, 0, 0, 0);
    }
    // lane: token = i0+m, d = g*4+r (o0) / 16+g*4+r (o1) -> two short4 stores
    size_t ob = ((size_t)(bw * NTOK + i0 + m)) * DIM + h * HD + g * 4;
    short4v s0, s1;
#pragma unroll
    for (int r = 0; r < 4; ++r) { s0[r] = f2bf(o0[r] * rv); s1[r] = f2bf(o1[r] * rv); }
    *(short4v*)(aout + ob) = s0;
    *(short4v*)(aout + ob + 16) = s1;
  }
}

// ---------------------------------------------------------------------------
// Proj GEMM (R3): same template as qkv_gemm. Block = 256 thr
// (4 waves x 48 ch = 192 out-ch); wave's 48x192 weight slice resident in
// registers (18 frags); grid-stride over 32-token tiles, double-buffered LDS
// ain staging with load-early/write-late. Lane stores float4 (16 B).
// ---------------------------------------------------------------------------
__global__ __launch_bounds__(256, 3) void proj_gemm(
    const short* __restrict__ ain, const short* __restrict__ pw,
    const float* __restrict__ pb, float* __restrict__ out)
{
  __shared__ __align__(16) short as_[2][32 * XPITCH];

  const int wave = threadIdx.x >> 6, lane = threadIdx.x & 63;
  const int m = lane & 15, g = lane >> 4;
  const int c0w = wave * 48;

  bf16x8 wfrag[3][6];
#pragma unroll
  for (int ct = 0; ct < 3; ++ct)
#pragma unroll
    for (int ks = 0; ks < 6; ++ks)
      wfrag[ct][ks] = *(const bf16x8*)(pw + (size_t)(c0w + ct * 16 + m) * DIM + ks * 32 + g * 8);

  float4 b4[3];
#pragma unroll
  for (int ct = 0; ct < 3; ++ct)
    b4[ct] = *(const float4*)(pb + c0w + ct * 16 + g * 4);

  // staging coords: 256 thr = 32 rows x 8 groups of 24 shorts (bf16 copy)
  const int srow = threadIdx.x >> 3;
  const int scg  = threadIdx.x & 7;

  { // prologue: stage first tile into buf 0
    const short* sp = ain + ((size_t)(blockIdx.x * 32 + srow)) * DIM + scg * 24;
    short* dp = &as_[0][srow * XPITCH + scg * 24];
#pragma unroll
    for (int i = 0; i < 3; ++i)
      *(bf16x8*)(dp + i * 8) = *(const bf16x8*)(sp + i * 8);
  }
  __syncthreads();

  int cur = 0;
  for (int t = blockIdx.x; t < NTILE; t += PROJ_GRID) {
    const int tn = t + PROJ_GRID;
    const bool have = tn < NTILE;
    bf16x8 r0, r1, r2;
    if (have) {       // issue next-tile loads early
      const short* sp = ain + ((size_t)(tn * 32 + srow)) * DIM + scg * 24;
      r0 = *(const bf16x8*)(sp);
      r1 = *(const bf16x8*)(sp + 8);
      r2 = *(const bf16x8*)(sp + 16);
    }

    f32x4 acc[3][2];
#pragma unroll
    for (int ct = 0; ct < 3; ++ct)
#pragma unroll
      for (int rt = 0; rt < 2; ++rt) acc[ct][rt] = (f32x4){0.f, 0.f, 0.f, 0.f};

#pragma unroll
    for (int ks = 0; ks < 6; ++ks) {
      const short* bp_ = &as_[cur][m * XPITCH + ks * 32 + g * 8];
      bf16x8 b0 = *(const bf16x8*)bp_;
      bf16x8 b1 = *(const bf16x8*)(bp_ + 16 * XPITCH);
#pragma unroll
      for (int ct = 0; ct < 3; ++ct) {
        acc[ct][0] = __builtin_amdgcn_mfma_f32_16x16x32_bf16(wfrag[ct][ks], b0, acc[ct][0], 0, 0, 0);
        acc[ct][1] = __builtin_amdgcn_mfma_f32_16x16x32_bf16(wfrag[ct][ks], b1, acc[ct][1], 0, 0, 0);
      }
    }

#pragma unroll
    for (int ct = 0; ct < 3; ++ct) {
      int co0 = c0w + ct * 16 + g * 4;
#pragma unroll
      for (int rt = 0; rt < 2; ++rt) {
        int tok = t * 32 + rt * 16 + m;
        float4 o;
        o.x = acc[ct][rt][0] + b4[ct].x;
        o.y = acc[ct][rt][1] + b4[ct].y;
        o.z = acc[ct][rt][2] + b4[ct].z;
        o.w = acc[ct][rt][3] + b4[ct].w;
        *(float4*)(out + (size_t)tok * DIM + co0) = o;
      }
    }

    if (have) {       // write-late into other buffer
      short* dp = &as_[cur ^ 1][srow * XPITCH + scg * 24];
      *(bf16x8*)(dp)      = r0;
      *(bf16x8*)(dp + 8)  = r1;
      *(bf16x8*)(dp + 16) = r2;
    }
    __syncthreads();
    cur ^= 1;
  }
}

// ---------------------------------------------------------------------------
extern "C" void kernel_launch(void* const* d_in, const int* in_sizes, int n_in,
                              void* d_out, int out_size, void* d_ws, size_t ws_size,
                              hipStream_t stream) {
  const float* x          = (const float*)d_in[0];
  const float* mask       = (const float*)d_in[1];
  const float* qkv_w      = (const float*)d_in[2];
  const float* qkv_b      = (const float*)d_in[3];
  const float* proj_w     = (const float*)d_in[4];
  const float* proj_b     = (const float*)d_in[5];
  const float* bias_table = (const float*)d_in[6];
  const int*   pos_index  = (const int*)d_in[7];
  float* out = (float*)d_out;

  // workspace carve (16B-aligned)
  const size_t NELEM = (size_t)TOKENS * DIM;   // 26,542,080
  short* qv    = (short*)d_ws;
  short* kv    = qv + NELEM;
  short* vv    = kv + NELEM;
  short* aout  = vv + NELEM;
  short* wqb   = aout + NELEM;
  short* wpb   = wqb + NWQ;
  short* biasT = wpb + NWP;
  short* maskT = biasT + NBIAS;
  // total = 4*NELEM + NWQ + NWP + NBIAS + NMASK shorts ≈ 260.4 MB

  prep_kernel<<<PREP_GRID, 256, 0, stream>>>(
      qkv_w, proj_w, bias_table, pos_index, mask, wqb, wpb, biasT, maskT);
  qkv_gemm<<<QKV_GRID, 768, 0, stream>>>(x, wqb, qkv_b, qv, kv, vv);
  attn_kernel<<<NBWH, 192, 0, stream>>>(qv, kv, vv, biasT, maskT, aout);
  proj_gemm<<<PROJ_GRID, 256, 0, stream>>>(aout, wpb, proj_b, out);
}